// Round 1
// baseline (4670.285 us; speedup 1.0000x reference)
//
#include <hip/hip_runtime.h>

#define NN_ 131072      // T*N
#define T_ 64
#define N_ 2048
#define E_ 2097152
#define FIN_ 16

// ---------------- init: deg = 1 (self loop), accum = 0 ----------------
__global__ void k_init(float* __restrict__ deg, float* __restrict__ accum) {
  int idx = blockIdx.x * 256 + threadIdx.x;
  if (idx < NN_) deg[idx] = 1.0f;
  if (idx < 2) accum[idx] = 0.0f;
}

// ---------------- degree accumulation over E edges ----------------
__global__ void k_deg(const int* __restrict__ col, float* __restrict__ deg) {
  int e = blockIdx.x * 256 + threadIdx.x;
  if (e < E_) unsafeAtomicAdd(&deg[col[e]], 1.0f);
}

__global__ void k_dinv(float* __restrict__ deg) {
  int v = blockIdx.x * 256 + threadIdx.x;
  if (v < NN_) deg[v] = rsqrtf(deg[v]);
}

// ---------------- GEMM (NN x K) @ (K x 64), fused self-loop agg init ----------------
template <int K>
__global__ void k_gemm_fused(const float* __restrict__ X, const float* __restrict__ W,
                             const float* __restrict__ dinv,
                             float* __restrict__ xw, float* __restrict__ agg) {
  int tid = threadIdx.x;
  int v = blockIdx.x * 4 + (tid >> 6);
  int j = tid & 63;
  const float* xr = X + (size_t)v * K;
  float acc = 0.f;
#pragma unroll
  for (int k = 0; k < K; ++k) acc = fmaf(xr[k], W[k * 64 + j], acc);
  float dv = dinv[v];
  size_t o = (size_t)v * 64 + j;
  xw[o] = acc;
  agg[o] = dv * dv * acc;   // self-loop contribution (norm = dinv[v]^2)
}

// ---------------- edge scatter: agg[col] += dinv[row]*dinv[col]*xw[row] ----------------
__global__ void k_scatter(const int* __restrict__ row, const int* __restrict__ col,
                          const float* __restrict__ dinv, const float* __restrict__ xw,
                          float* __restrict__ agg) {
  int e = blockIdx.x * 4 + (threadIdx.x >> 6);
  int lane = threadIdx.x & 63;
  int r = row[e], c = col[e];
  float nrm = dinv[r] * dinv[c];
  float val = nrm * xw[(size_t)r * 64 + lane];
  unsafeAtomicAdd(&agg[(size_t)c * 64 + lane], val);
}

// ---------------- bias + relu in place ----------------
__global__ void k_bias_relu(float* __restrict__ h, const float* __restrict__ b) {
  size_t idx = (size_t)blockIdx.x * 256 + threadIdx.x;
  int j = (int)(idx & 63);
  float v = h[idx] + b[j];
  h[idx] = v > 0.f ? v : 0.f;
}

// ---------------- persistent bidirectional LSTM ----------------
// grid = 128 blocks: blockIdx & 63 = batch b (= original t), blockIdx >> 6 = dir.
// xs[s][b][k] = h2[(b*N_ + s)*64 + k].  y layout (t, n, 128); fwd at +0, bwd at +64.
__global__ __launch_bounds__(256) void k_lstm(
    const float* __restrict__ h2,
    const float* __restrict__ WihF, const float* __restrict__ WhhF,
    const float* __restrict__ bihF, const float* __restrict__ bhhF,
    const float* __restrict__ WihB, const float* __restrict__ WhhB,
    const float* __restrict__ bihB, const float* __restrict__ bhhB,
    float* __restrict__ y) {
  const int b   = blockIdx.x & 63;
  const int dir = blockIdx.x >> 6;
  const float* Wih = dir ? WihB : WihF;
  const float* Whh = dir ? WhhB : WhhF;
  const float* bih = dir ? bihB : bihF;
  const float* bhh = dir ? bhhB : bhhF;
  const int j = threadIdx.x;   // gate index 0..255  (i: 0-63, f: 64-127, g: 128-191, o: 192-255)

  float wih[64], whh[64];
#pragma unroll
  for (int k = 0; k < 64; k += 4) {
    *reinterpret_cast<float4*>(&wih[k]) = *reinterpret_cast<const float4*>(&Wih[j * 64 + k]);
    *reinterpret_cast<float4*>(&whh[k]) = *reinterpret_cast<const float4*>(&Whh[j * 64 + k]);
  }
  const float bias = bih[j] + bhh[j];

  __shared__ __align__(16) float xbuf[64];
  __shared__ __align__(16) float hbuf[64];
  __shared__ float gbuf[256];
  float c = 0.f;
  if (j < 64) hbuf[j] = 0.f;
  __syncthreads();

  for (int si = 0; si < N_; ++si) {
    const int s = dir ? (N_ - 1 - si) : si;
    const size_t vrow = (size_t)b * N_ + s;
    if (j < 64) xbuf[j] = h2[vrow * 64 + j];
    __syncthreads();                      // B1: xbuf staged, hbuf from prev step visible

    float a0 = 0.f, a1 = 0.f, a2 = 0.f, a3 = 0.f;
#pragma unroll
    for (int k = 0; k < 64; k += 16) {
      float4 xv0 = *reinterpret_cast<const float4*>(&xbuf[k]);
      float4 hv0 = *reinterpret_cast<const float4*>(&hbuf[k]);
      a0 = fmaf(xv0.x, wih[k+0], a0); a0 = fmaf(hv0.x, whh[k+0], a0);
      a0 = fmaf(xv0.y, wih[k+1], a0); a0 = fmaf(hv0.y, whh[k+1], a0);
      a0 = fmaf(xv0.z, wih[k+2], a0); a0 = fmaf(hv0.z, whh[k+2], a0);
      a0 = fmaf(xv0.w, wih[k+3], a0); a0 = fmaf(hv0.w, whh[k+3], a0);
      float4 xv1 = *reinterpret_cast<const float4*>(&xbuf[k+4]);
      float4 hv1 = *reinterpret_cast<const float4*>(&hbuf[k+4]);
      a1 = fmaf(xv1.x, wih[k+4], a1); a1 = fmaf(hv1.x, whh[k+4], a1);
      a1 = fmaf(xv1.y, wih[k+5], a1); a1 = fmaf(hv1.y, whh[k+5], a1);
      a1 = fmaf(xv1.z, wih[k+6], a1); a1 = fmaf(hv1.z, whh[k+6], a1);
      a1 = fmaf(xv1.w, wih[k+7], a1); a1 = fmaf(hv1.w, whh[k+7], a1);
      float4 xv2 = *reinterpret_cast<const float4*>(&xbuf[k+8]);
      float4 hv2 = *reinterpret_cast<const float4*>(&hbuf[k+8]);
      a2 = fmaf(xv2.x, wih[k+8], a2); a2 = fmaf(hv2.x, whh[k+8], a2);
      a2 = fmaf(xv2.y, wih[k+9], a2); a2 = fmaf(hv2.y, whh[k+9], a2);
      a2 = fmaf(xv2.z, wih[k+10], a2); a2 = fmaf(hv2.z, whh[k+10], a2);
      a2 = fmaf(xv2.w, wih[k+11], a2); a2 = fmaf(hv2.w, whh[k+11], a2);
      float4 xv3 = *reinterpret_cast<const float4*>(&xbuf[k+12]);
      float4 hv3 = *reinterpret_cast<const float4*>(&hbuf[k+12]);
      a3 = fmaf(xv3.x, wih[k+12], a3); a3 = fmaf(hv3.x, whh[k+12], a3);
      a3 = fmaf(xv3.y, wih[k+13], a3); a3 = fmaf(hv3.y, whh[k+13], a3);
      a3 = fmaf(xv3.z, wih[k+14], a3); a3 = fmaf(hv3.z, whh[k+14], a3);
      a3 = fmaf(xv3.w, wih[k+15], a3); a3 = fmaf(hv3.w, whh[k+15], a3);
    }
    gbuf[j] = bias + (a0 + a1) + (a2 + a3);
    __syncthreads();                      // B2: all gates written

    if (j < 64) {
      float gi = gbuf[j], gf = gbuf[64 + j], gg = gbuf[128 + j], go = gbuf[192 + j];
      float si_ = 1.f / (1.f + expf(-gi));
      float sf  = 1.f / (1.f + expf(-gf));
      float so  = 1.f / (1.f + expf(-go));
      float tg  = tanhf(gg);
      c = sf * c + si_ * tg;
      float hh = so * tanhf(c);
      hbuf[j] = hh;
      y[vrow * 128 + (size_t)dir * 64 + j] = hh;
    }
    // next iteration's B1 orders hbuf writes before gate reads; gbuf reads
    // (before next B1) are safe against next gate writes (after next B1).
  }
}

// ---------------- decoder + masked MSE reduction ----------------
__global__ void k_decoder(const float* __restrict__ y, const float* __restrict__ x,
                          const float* __restrict__ mask, const float* __restrict__ Wd,
                          const float* __restrict__ bd, float* __restrict__ out,
                          float* __restrict__ accum) {
  int tid = threadIdx.x;
  size_t v = (size_t)blockIdx.x * 16 + (tid >> 4);
  int f = tid & 15;
  const float* yr = y + v * 128;
  float acc = bd[f];
#pragma unroll
  for (int jj = 0; jj < 128; jj += 4) {
    float4 yv = *reinterpret_cast<const float4*>(&yr[jj]);
    float4 wv = *reinterpret_cast<const float4*>(&Wd[f * 128 + jj]);
    acc = fmaf(yv.x, wv.x, acc); acc = fmaf(yv.y, wv.y, acc);
    acc = fmaf(yv.z, wv.z, acc); acc = fmaf(yv.w, wv.w, acc);
  }
  size_t o = v * 16 + f;
  float xv = x[o], m = mask[o];
  float d = acc - xv;
  out[o] = (m != 0.f) ? xv : acc;
  float num = m * d * d;
  float den = m;
#pragma unroll
  for (int off = 32; off > 0; off >>= 1) {
    num += __shfl_down(num, off);
    den += __shfl_down(den, off);
  }
  if ((tid & 63) == 0) {
    unsafeAtomicAdd(&accum[0], num);
    unsafeAtomicAdd(&accum[1], den);
  }
}

__global__ void k_loss(const float* __restrict__ accum, float* __restrict__ out_loss) {
  if (threadIdx.x == 0) out_loss[0] = accum[0] / (accum[1] + 1e-8f);
}

// ---------------- launch ----------------
extern "C" void kernel_launch(void* const* d_in, const int* in_sizes, int n_in,
                              void* d_out, int out_size, void* d_ws, size_t ws_size,
                              hipStream_t stream) {
  const float* x    = (const float*)d_in[0];
  const int*   ei   = (const int*)d_in[1];      // (2, E): row = ei, col = ei + E_
  const float* mask = (const float*)d_in[2];
  const float* W1 = (const float*)d_in[3];
  const float* b1 = (const float*)d_in[4];
  const float* W2 = (const float*)d_in[5];
  const float* b2 = (const float*)d_in[6];
  const float* WihF = (const float*)d_in[7];
  const float* WhhF = (const float*)d_in[8];
  const float* bihF = (const float*)d_in[9];
  const float* bhhF = (const float*)d_in[10];
  const float* WihB = (const float*)d_in[11];
  const float* WhhB = (const float*)d_in[12];
  const float* bihB = (const float*)d_in[13];
  const float* bhhB = (const float*)d_in[14];
  const float* Wd = (const float*)d_in[15];
  const float* bd = (const float*)d_in[16];
  float* out = (float*)d_out;

  char* ws = (char*)d_ws;
  float* dinv  = (float*)ws; ws += (size_t)NN_ * 4;
  float* accum = (float*)ws; ws += 256;
  float* bufA  = (float*)ws; ws += (size_t)NN_ * 64 * 4;
  float* bufB  = (float*)ws; ws += (size_t)NN_ * 64 * 4;
  float* bufC  = (float*)ws; ws += (size_t)NN_ * 64 * 4;
  float* y     = (float*)ws; ws += (size_t)NN_ * 128 * 4;

  // degrees (with self loop) -> dinv
  k_init<<<NN_ / 256, 256, 0, stream>>>(dinv, accum);
  k_deg<<<E_ / 256, 256, 0, stream>>>(ei + E_, dinv);
  k_dinv<<<NN_ / 256, 256, 0, stream>>>(dinv);

  // GCN layer 1: xw1 -> bufA, agg1 (self-loop init) -> bufB
  k_gemm_fused<FIN_><<<NN_ / 4, 256, 0, stream>>>(x, W1, dinv, bufA, bufB);
  k_scatter<<<E_ / 4, 256, 0, stream>>>(ei, ei + E_, dinv, bufA, bufB);
  k_bias_relu<<<(size_t)NN_ * 64 / 256, 256, 0, stream>>>(bufB, b1);   // h1 in bufB

  // GCN layer 2: xw2 -> bufC, agg2 -> bufA (xw1 dead)
  k_gemm_fused<64><<<NN_ / 4, 256, 0, stream>>>(bufB, W2, dinv, bufC, bufA);
  k_scatter<<<E_ / 4, 256, 0, stream>>>(ei, ei + E_, dinv, bufC, bufA);
  k_bias_relu<<<(size_t)NN_ * 64 / 256, 256, 0, stream>>>(bufA, b2);   // h2 in bufA

  // bidirectional LSTM: 128 persistent blocks
  k_lstm<<<128, 256, 0, stream>>>(bufA, WihF, WhhF, bihF, bhhF,
                                  WihB, WhhB, bihB, bhhB, y);

  // decoder + loss
  k_decoder<<<NN_ / 16, 256, 0, stream>>>(y, x, mask, Wd, bd, out, accum);
  k_loss<<<1, 64, 0, stream>>>(accum, out + (size_t)NN_ * FIN_);
}

// Round 2
// 4230.697 us; speedup vs baseline: 1.1039x; 1.1039x over previous
//
#include <hip/hip_runtime.h>

#define NN_ 131072      // T*N
#define T_ 64
#define N_ 2048
#define E_ 2097152
#define FIN_ 16

// ---------------- init: deg = 1 (self loop), accum = 0 ----------------
__global__ void k_init(float* __restrict__ deg, float* __restrict__ accum) {
  int idx = blockIdx.x * 256 + threadIdx.x;
  if (idx < NN_) deg[idx] = 1.0f;
  if (idx < 2) accum[idx] = 0.0f;
}

// ---------------- degree accumulation over E edges ----------------
__global__ void k_deg(const int* __restrict__ col, float* __restrict__ deg) {
  int e = blockIdx.x * 256 + threadIdx.x;
  if (e < E_) unsafeAtomicAdd(&deg[col[e]], 1.0f);
}

__global__ void k_dinv(float* __restrict__ deg) {
  int v = blockIdx.x * 256 + threadIdx.x;
  if (v < NN_) deg[v] = rsqrtf(deg[v]);
}

// ---------------- GEMM (NN x K) @ (K x 64), fused self-loop agg init ----------------
template <int K>
__global__ void k_gemm_fused(const float* __restrict__ X, const float* __restrict__ W,
                             const float* __restrict__ dinv,
                             float* __restrict__ xw, float* __restrict__ agg) {
  int tid = threadIdx.x;
  int v = blockIdx.x * 4 + (tid >> 6);
  int j = tid & 63;
  const float* xr = X + (size_t)v * K;
  float acc = 0.f;
#pragma unroll
  for (int k = 0; k < K; ++k) acc = fmaf(xr[k], W[k * 64 + j], acc);
  float dv = dinv[v];
  size_t o = (size_t)v * 64 + j;
  xw[o] = acc;
  agg[o] = dv * dv * acc;   // self-loop contribution (norm = dinv[v]^2)
}

// ---------------- edge scatter: agg[col] += dinv[row]*dinv[col]*xw[row] ----------------
__global__ void k_scatter(const int* __restrict__ row, const int* __restrict__ col,
                          const float* __restrict__ dinv, const float* __restrict__ xw,
                          float* __restrict__ agg) {
  int e = blockIdx.x * 4 + (threadIdx.x >> 6);
  int lane = threadIdx.x & 63;
  int r = row[e], c = col[e];
  float nrm = dinv[r] * dinv[c];
  float val = nrm * xw[(size_t)r * 64 + lane];
  unsafeAtomicAdd(&agg[(size_t)c * 64 + lane], val);
}

// ---------------- bias + relu in place ----------------
__global__ void k_bias_relu(float* __restrict__ h, const float* __restrict__ b) {
  size_t idx = (size_t)blockIdx.x * 256 + threadIdx.x;
  int j = (int)(idx & 63);
  float v = h[idx] + b[j];
  h[idx] = v > 0.f ? v : 0.f;
}

// ---------------- persistent bidirectional LSTM ----------------
// grid = 128 blocks: blockIdx & 63 = batch b (= original t), blockIdx >> 6 = dir.
// xs[s][b][k] = h2[(b*N_ + s)*64 + k].  y layout (t, n, 128); fwd at +0, bwd at +64.
__global__ __launch_bounds__(256) void k_lstm(
    const float* __restrict__ h2,
    const float* __restrict__ WihF, const float* __restrict__ WhhF,
    const float* __restrict__ bihF, const float* __restrict__ bhhF,
    const float* __restrict__ WihB, const float* __restrict__ WhhB,
    const float* __restrict__ bihB, const float* __restrict__ bhhB,
    float* __restrict__ y) {
  const int b   = blockIdx.x & 63;
  const int dir = blockIdx.x >> 6;
  const float* Wih = dir ? WihB : WihF;
  const float* Whh = dir ? WhhB : WhhF;
  const float* bih = dir ? bihB : bihF;
  const float* bhh = dir ? bhhB : bhhF;
  const int j = threadIdx.x;   // gate index 0..255  (i: 0-63, f: 64-127, g: 128-191, o: 192-255)

  float wih[64], whh[64];
#pragma unroll
  for (int k = 0; k < 64; k += 4) {
    *reinterpret_cast<float4*>(&wih[k]) = *reinterpret_cast<const float4*>(&Wih[j * 64 + k]);
    *reinterpret_cast<float4*>(&whh[k]) = *reinterpret_cast<const float4*>(&Whh[j * 64 + k]);
  }
  const float bias = bih[j] + bhh[j];

  __shared__ __align__(16) float xbuf[64];
  __shared__ __align__(16) float hbuf[64];
  __shared__ float gbuf[256];
  float c = 0.f;
  if (j < 64) hbuf[j] = 0.f;

  // preload x for step 0 (wave 0 only)
  float xr = 0.f;
  if (j < 64) xr = h2[((size_t)b * N_ + (dir ? N_ - 1 : 0)) * 64 + j];
  __syncthreads();   // hbuf init visible

  for (int si = 0; si < N_; ++si) {
    const int s = dir ? (N_ - 1 - si) : si;
    const size_t vrow = (size_t)b * N_ + s;
    if (j < 64) xbuf[j] = xr;
    __syncthreads();                      // B1: xbuf staged, hbuf from prev step visible

    // prefetch next step's x row; latency hides under FMA + activation phases
    float xr_next = xr;
    {
      const int si2 = (si + 1 < N_) ? si + 1 : si;
      const int s2 = dir ? (N_ - 1 - si2) : si2;
      if (j < 64) xr_next = h2[((size_t)b * N_ + s2) * 64 + j];
    }

    float a0 = 0.f, a1 = 0.f, a2 = 0.f, a3 = 0.f;
#pragma unroll
    for (int k = 0; k < 64; k += 16) {
      float4 xv0 = *reinterpret_cast<const float4*>(&xbuf[k]);
      float4 hv0 = *reinterpret_cast<const float4*>(&hbuf[k]);
      a0 = fmaf(xv0.x, wih[k+0], a0); a0 = fmaf(hv0.x, whh[k+0], a0);
      a0 = fmaf(xv0.y, wih[k+1], a0); a0 = fmaf(hv0.y, whh[k+1], a0);
      a0 = fmaf(xv0.z, wih[k+2], a0); a0 = fmaf(hv0.z, whh[k+2], a0);
      a0 = fmaf(xv0.w, wih[k+3], a0); a0 = fmaf(hv0.w, whh[k+3], a0);
      float4 xv1 = *reinterpret_cast<const float4*>(&xbuf[k+4]);
      float4 hv1 = *reinterpret_cast<const float4*>(&hbuf[k+4]);
      a1 = fmaf(xv1.x, wih[k+4], a1); a1 = fmaf(hv1.x, whh[k+4], a1);
      a1 = fmaf(xv1.y, wih[k+5], a1); a1 = fmaf(hv1.y, whh[k+5], a1);
      a1 = fmaf(xv1.z, wih[k+6], a1); a1 = fmaf(hv1.z, whh[k+6], a1);
      a1 = fmaf(xv1.w, wih[k+7], a1); a1 = fmaf(hv1.w, whh[k+7], a1);
      float4 xv2 = *reinterpret_cast<const float4*>(&xbuf[k+8]);
      float4 hv2 = *reinterpret_cast<const float4*>(&hbuf[k+8]);
      a2 = fmaf(xv2.x, wih[k+8], a2); a2 = fmaf(hv2.x, whh[k+8], a2);
      a2 = fmaf(xv2.y, wih[k+9], a2); a2 = fmaf(hv2.y, whh[k+9], a2);
      a2 = fmaf(xv2.z, wih[k+10], a2); a2 = fmaf(hv2.z, whh[k+10], a2);
      a2 = fmaf(xv2.w, wih[k+11], a2); a2 = fmaf(hv2.w, whh[k+11], a2);
      float4 xv3 = *reinterpret_cast<const float4*>(&xbuf[k+12]);
      float4 hv3 = *reinterpret_cast<const float4*>(&hbuf[k+12]);
      a3 = fmaf(xv3.x, wih[k+12], a3); a3 = fmaf(hv3.x, whh[k+12], a3);
      a3 = fmaf(xv3.y, wih[k+13], a3); a3 = fmaf(hv3.y, whh[k+13], a3);
      a3 = fmaf(xv3.z, wih[k+14], a3); a3 = fmaf(hv3.z, whh[k+14], a3);
      a3 = fmaf(xv3.w, wih[k+15], a3); a3 = fmaf(hv3.w, whh[k+15], a3);
    }
    gbuf[j] = bias + (a0 + a1) + (a2 + a3);
    __syncthreads();                      // B2: all gates written

    if (j < 64) {
      float gi = gbuf[j], gf = gbuf[64 + j], gg = gbuf[128 + j], go = gbuf[192 + j];
      // fast sigmoid/tanh: v_exp + v_rcp based
      float si_ = __fdividef(1.f, 1.f + __expf(-gi));
      float sf  = __fdividef(1.f, 1.f + __expf(-gf));
      float so  = __fdividef(1.f, 1.f + __expf(-go));
      float tg  = 1.f - __fdividef(2.f, __expf(2.f * gg) + 1.f);
      c = sf * c + si_ * tg;
      float tc = 1.f - __fdividef(2.f, __expf(2.f * c) + 1.f);
      float hh = so * tc;
      hbuf[j] = hh;
      y[vrow * 128 + (size_t)dir * 64 + j] = hh;
    }
    xr = xr_next;
    // next iteration's B1 orders hbuf writes before gate reads; gbuf reads
    // (wave 0, before its B1 arrival) are safe against next writes (after B1).
  }
}

// ---------------- decoder + masked MSE reduction ----------------
__global__ void k_decoder(const float* __restrict__ y, const float* __restrict__ x,
                          const float* __restrict__ mask, const float* __restrict__ Wd,
                          const float* __restrict__ bd, float* __restrict__ out,
                          float* __restrict__ accum) {
  int tid = threadIdx.x;
  size_t v = (size_t)blockIdx.x * 16 + (tid >> 4);
  int f = tid & 15;
  const float* yr = y + v * 128;
  float acc = bd[f];
#pragma unroll
  for (int jj = 0; jj < 128; jj += 4) {
    float4 yv = *reinterpret_cast<const float4*>(&yr[jj]);
    float4 wv = *reinterpret_cast<const float4*>(&Wd[f * 128 + jj]);
    acc = fmaf(yv.x, wv.x, acc); acc = fmaf(yv.y, wv.y, acc);
    acc = fmaf(yv.z, wv.z, acc); acc = fmaf(yv.w, wv.w, acc);
  }
  size_t o = v * 16 + f;
  float xv = x[o], m = mask[o];
  float d = acc - xv;
  out[o] = (m != 0.f) ? xv : acc;
  float num = m * d * d;
  float den = m;
#pragma unroll
  for (int off = 32; off > 0; off >>= 1) {
    num += __shfl_down(num, off);
    den += __shfl_down(den, off);
  }
  if ((tid & 63) == 0) {
    unsafeAtomicAdd(&accum[0], num);
    unsafeAtomicAdd(&accum[1], den);
  }
}

__global__ void k_loss(const float* __restrict__ accum, float* __restrict__ out_loss) {
  if (threadIdx.x == 0) out_loss[0] = accum[0] / (accum[1] + 1e-8f);
}

// ---------------- launch ----------------
extern "C" void kernel_launch(void* const* d_in, const int* in_sizes, int n_in,
                              void* d_out, int out_size, void* d_ws, size_t ws_size,
                              hipStream_t stream) {
  const float* x    = (const float*)d_in[0];
  const int*   ei   = (const int*)d_in[1];      // (2, E): row = ei, col = ei + E_
  const float* mask = (const float*)d_in[2];
  const float* W1 = (const float*)d_in[3];
  const float* b1 = (const float*)d_in[4];
  const float* W2 = (const float*)d_in[5];
  const float* b2 = (const float*)d_in[6];
  const float* WihF = (const float*)d_in[7];
  const float* WhhF = (const float*)d_in[8];
  const float* bihF = (const float*)d_in[9];
  const float* bhhF = (const float*)d_in[10];
  const float* WihB = (const float*)d_in[11];
  const float* WhhB = (const float*)d_in[12];
  const float* bihB = (const float*)d_in[13];
  const float* bhhB = (const float*)d_in[14];
  const float* Wd = (const float*)d_in[15];
  const float* bd = (const float*)d_in[16];
  float* out = (float*)d_out;

  char* ws = (char*)d_ws;
  float* dinv  = (float*)ws; ws += (size_t)NN_ * 4;
  float* accum = (float*)ws; ws += 256;
  float* bufA  = (float*)ws; ws += (size_t)NN_ * 64 * 4;
  float* bufB  = (float*)ws; ws += (size_t)NN_ * 64 * 4;
  float* bufC  = (float*)ws; ws += (size_t)NN_ * 64 * 4;
  float* y     = (float*)ws; ws += (size_t)NN_ * 128 * 4;

  // degrees (with self loop) -> dinv
  k_init<<<NN_ / 256, 256, 0, stream>>>(dinv, accum);
  k_deg<<<E_ / 256, 256, 0, stream>>>(ei + E_, dinv);
  k_dinv<<<NN_ / 256, 256, 0, stream>>>(dinv);

  // GCN layer 1: xw1 -> bufA, agg1 (self-loop init) -> bufB
  k_gemm_fused<FIN_><<<NN_ / 4, 256, 0, stream>>>(x, W1, dinv, bufA, bufB);
  k_scatter<<<E_ / 4, 256, 0, stream>>>(ei, ei + E_, dinv, bufA, bufB);
  k_bias_relu<<<(size_t)NN_ * 64 / 256, 256, 0, stream>>>(bufB, b1);   // h1 in bufB

  // GCN layer 2: xw2 -> bufC, agg2 -> bufA (xw1 dead)
  k_gemm_fused<64><<<NN_ / 4, 256, 0, stream>>>(bufB, W2, dinv, bufC, bufA);
  k_scatter<<<E_ / 4, 256, 0, stream>>>(ei, ei + E_, dinv, bufC, bufA);
  k_bias_relu<<<(size_t)NN_ * 64 / 256, 256, 0, stream>>>(bufA, b2);   // h2 in bufA

  // bidirectional LSTM: 128 persistent blocks
  k_lstm<<<128, 256, 0, stream>>>(bufA, WihF, WhhF, bihF, bhhF,
                                  WihB, WhhB, bihB, bhhB, y);

  // decoder + loss
  k_decoder<<<NN_ / 16, 256, 0, stream>>>(y, x, mask, Wd, bd, out, accum);
  k_loss<<<1, 64, 0, stream>>>(accum, out + (size_t)NN_ * FIN_);
}

// Round 3
// 4191.447 us; speedup vs baseline: 1.1142x; 1.0094x over previous
//
#include <hip/hip_runtime.h>

#define NN_ 131072      // T*N
#define T_ 64
#define N_ 2048
#define E_ 2097152
#define FIN_ 16

// LDS-only barrier: publishes LDS writes, does NOT drain vmcnt (prefetches /
// stores stay in flight across it). Memory clobber pins LDS ops in-phase.
#define LBAR() asm volatile("s_waitcnt lgkmcnt(0)\n\ts_barrier" ::: "memory")

// ---------------- init: deg = 1 (self loop), accum = 0 ----------------
__global__ void k_init(float* __restrict__ deg, float* __restrict__ accum) {
  int idx = blockIdx.x * 256 + threadIdx.x;
  if (idx < NN_) deg[idx] = 1.0f;
  if (idx < 2) accum[idx] = 0.0f;
}

// ---------------- degree accumulation over E edges ----------------
__global__ void k_deg(const int* __restrict__ col, float* __restrict__ deg) {
  int e = blockIdx.x * 256 + threadIdx.x;
  if (e < E_) unsafeAtomicAdd(&deg[col[e]], 1.0f);
}

__global__ void k_dinv(float* __restrict__ deg) {
  int v = blockIdx.x * 256 + threadIdx.x;
  if (v < NN_) deg[v] = rsqrtf(deg[v]);
}

// ---------------- GEMM (NN x K) @ (K x 64), fused self-loop agg init ----------
// Optionally applies relu(x + bin) to the input rows while staging (fuses the
// previous layer's bias+relu pass).
template <int K, bool RELU_IN>
__global__ void k_gemm(const float* __restrict__ X, const float* __restrict__ W,
                       const float* __restrict__ bin, const float* __restrict__ dinv,
                       float* __restrict__ xw, float* __restrict__ agg) {
  __shared__ float xs[4 * K];
  const int tid = threadIdx.x;
  const int v0 = blockIdx.x * 4;
  for (int t = tid; t < 4 * K; t += 256) {
    float v = X[(size_t)v0 * K + t];
    if (RELU_IN) v = fmaxf(v + bin[t & (K - 1)], 0.f);
    xs[t] = v;
  }
  __syncthreads();
  const int v = v0 + (tid >> 6);
  const int j = tid & 63;
  const float* xr = &xs[(tid >> 6) * K];
  float acc = 0.f;
#pragma unroll
  for (int k = 0; k < K; ++k) acc = fmaf(xr[k], W[k * 64 + j], acc);
  float dv = dinv[v];
  size_t o = (size_t)v * 64 + j;
  xw[o] = acc;
  agg[o] = dv * dv * acc;   // self-loop contribution (norm = dinv[v]^2)
}

// ---------------- edge scatter: agg[col] += dinv[row]*dinv[col]*xw[row] -------
__global__ void k_scatter(const int* __restrict__ row, const int* __restrict__ col,
                          const float* __restrict__ dinv, const float* __restrict__ xw,
                          float* __restrict__ agg) {
  int e = blockIdx.x * 4 + (threadIdx.x >> 6);
  int lane = threadIdx.x & 63;
  int r = row[e], c = col[e];
  float nrm = dinv[r] * dinv[c];
  float val = nrm * xw[(size_t)r * 64 + lane];
  unsafeAtomicAdd(&agg[(size_t)c * 64 + lane], val);
}

// ---------------- persistent bidirectional LSTM ----------------
// grid = 128 blocks: blockIdx & 63 = batch b (= original t), blockIdx >> 6 = dir.
// Input is RAW agg2 (pre-bias); relu(x + b2) fused at staging.
// y layout (t, n, 128); fwd at +0, bwd at +64.
__global__ __launch_bounds__(256) void k_lstm(
    const float* __restrict__ h2raw, const float* __restrict__ b2,
    const float* __restrict__ WihF, const float* __restrict__ WhhF,
    const float* __restrict__ bihF, const float* __restrict__ bhhF,
    const float* __restrict__ WihB, const float* __restrict__ WhhB,
    const float* __restrict__ bihB, const float* __restrict__ bhhB,
    float* __restrict__ y) {
  const int b   = blockIdx.x & 63;
  const int dir = blockIdx.x >> 6;
  const float* Wih = dir ? WihB : WihF;
  const float* Whh = dir ? WhhB : WhhF;
  const float* bih = dir ? bihB : bihF;
  const float* bhh = dir ? bhhB : bhhF;
  const int j = threadIdx.x;   // gate index 0..255 (i:0-63 f:64-127 g:128-191 o:192-255)

  float wih[64], whh[64];
#pragma unroll
  for (int k = 0; k < 64; k += 4) {
    *reinterpret_cast<float4*>(&wih[k]) = *reinterpret_cast<const float4*>(&Wih[j * 64 + k]);
    *reinterpret_cast<float4*>(&whh[k]) = *reinterpret_cast<const float4*>(&Whh[j * 64 + k]);
  }
  const float bias = bih[j] + bhh[j];
  const float b2j = (j < 64) ? b2[j] : 0.f;

  __shared__ __align__(16) float xbuf[64];
  __shared__ __align__(16) float hbuf[64];
  __shared__ float gbuf[256];
  float c = 0.f;
  if (j < 64) hbuf[j] = 0.f;

  // preload x for steps 0 and 1 (raw, wave 0 only)
  float xc = 0.f, xn = 0.f;
  if (j < 64) {
    const int s0 = dir ? N_ - 1 : 0;
    const int s1 = dir ? N_ - 2 : 1;
    xc = h2raw[((size_t)b * N_ + s0) * 64 + j];
    xn = h2raw[((size_t)b * N_ + s1) * 64 + j];
  }

  for (int si = 0; si < N_; ++si) {
    const int s = dir ? (N_ - 1 - si) : si;
    const size_t vrow = (size_t)b * N_ + s;
    if (j < 64) xbuf[j] = fmaxf(xc + b2j, 0.f);
    LBAR();                               // B1: xbuf + prev hbuf published

    // prefetch x for step si+2 — has ~2 full steps to complete, never drained
    float xp = 0.f;
    {
      int si2 = si + 2; if (si2 >= N_) si2 = N_ - 1;
      const int s2 = dir ? (N_ - 1 - si2) : si2;
      if (j < 64) xp = h2raw[((size_t)b * N_ + s2) * 64 + j];
    }

    float a0 = 0.f, a1 = 0.f, a2 = 0.f, a3 = 0.f;
#pragma unroll
    for (int k = 0; k < 64; k += 16) {
      float4 xv0 = *reinterpret_cast<const float4*>(&xbuf[k]);
      float4 hv0 = *reinterpret_cast<const float4*>(&hbuf[k]);
      a0 = fmaf(xv0.x, wih[k+0], a0); a0 = fmaf(hv0.x, whh[k+0], a0);
      a0 = fmaf(xv0.y, wih[k+1], a0); a0 = fmaf(hv0.y, whh[k+1], a0);
      a0 = fmaf(xv0.z, wih[k+2], a0); a0 = fmaf(hv0.z, whh[k+2], a0);
      a0 = fmaf(xv0.w, wih[k+3], a0); a0 = fmaf(hv0.w, whh[k+3], a0);
      float4 xv1 = *reinterpret_cast<const float4*>(&xbuf[k+4]);
      float4 hv1 = *reinterpret_cast<const float4*>(&hbuf[k+4]);
      a1 = fmaf(xv1.x, wih[k+4], a1); a1 = fmaf(hv1.x, whh[k+4], a1);
      a1 = fmaf(xv1.y, wih[k+5], a1); a1 = fmaf(hv1.y, whh[k+5], a1);
      a1 = fmaf(xv1.z, wih[k+6], a1); a1 = fmaf(hv1.z, whh[k+6], a1);
      a1 = fmaf(xv1.w, wih[k+7], a1); a1 = fmaf(hv1.w, whh[k+7], a1);
      float4 xv2 = *reinterpret_cast<const float4*>(&xbuf[k+8]);
      float4 hv2 = *reinterpret_cast<const float4*>(&hbuf[k+8]);
      a2 = fmaf(xv2.x, wih[k+8], a2); a2 = fmaf(hv2.x, whh[k+8], a2);
      a2 = fmaf(xv2.y, wih[k+9], a2); a2 = fmaf(hv2.y, whh[k+9], a2);
      a2 = fmaf(xv2.z, wih[k+10], a2); a2 = fmaf(hv2.z, whh[k+10], a2);
      a2 = fmaf(xv2.w, wih[k+11], a2); a2 = fmaf(hv2.w, whh[k+11], a2);
      float4 xv3 = *reinterpret_cast<const float4*>(&xbuf[k+12]);
      float4 hv3 = *reinterpret_cast<const float4*>(&hbuf[k+12]);
      a3 = fmaf(xv3.x, wih[k+12], a3); a3 = fmaf(hv3.x, whh[k+12], a3);
      a3 = fmaf(xv3.y, wih[k+13], a3); a3 = fmaf(hv3.y, whh[k+13], a3);
      a3 = fmaf(xv3.z, wih[k+14], a3); a3 = fmaf(hv3.z, whh[k+14], a3);
      a3 = fmaf(xv3.w, wih[k+15], a3); a3 = fmaf(hv3.w, whh[k+15], a3);
    }
    gbuf[j] = bias + (a0 + a1) + (a2 + a3);
    LBAR();                               // B2: all gates published

    if (j < 64) {
      float gi = gbuf[j], gf = gbuf[64 + j], gg = gbuf[128 + j], go = gbuf[192 + j];
      float si_ = __fdividef(1.f, 1.f + __expf(-gi));
      float sf  = __fdividef(1.f, 1.f + __expf(-gf));
      float so  = __fdividef(1.f, 1.f + __expf(-go));
      float tg  = 1.f - __fdividef(2.f, __expf(2.f * gg) + 1.f);
      c = sf * c + si_ * tg;
      float tc = 1.f - __fdividef(2.f, __expf(2.f * c) + 1.f);
      float hh = so * tc;
      hbuf[j] = hh;
      y[vrow * 128 + (size_t)dir * 64 + j] = hh;   // store floats in vmem queue
    }
    xc = xn; xn = xp;
    // wave0's gbuf reads happen before its B1(si+1) arrival; other waves write
    // gbuf only after B1(si+1) releases (requires wave0's arrival) -> safe.
  }
}

// ---------------- decoder + masked MSE reduction ----------------
__global__ void k_decoder(const float* __restrict__ y, const float* __restrict__ x,
                          const float* __restrict__ mask, const float* __restrict__ Wd,
                          const float* __restrict__ bd, float* __restrict__ out,
                          float* __restrict__ accum) {
  int tid = threadIdx.x;
  size_t v = (size_t)blockIdx.x * 16 + (tid >> 4);
  int f = tid & 15;
  const float* yr = y + v * 128;
  float acc = bd[f];
#pragma unroll
  for (int jj = 0; jj < 128; jj += 4) {
    float4 yv = *reinterpret_cast<const float4*>(&yr[jj]);
    float4 wv = *reinterpret_cast<const float4*>(&Wd[f * 128 + jj]);
    acc = fmaf(yv.x, wv.x, acc); acc = fmaf(yv.y, wv.y, acc);
    acc = fmaf(yv.z, wv.z, acc); acc = fmaf(yv.w, wv.w, acc);
  }
  size_t o = v * 16 + f;
  float xv = x[o], m = mask[o];
  float d = acc - xv;
  out[o] = (m != 0.f) ? xv : acc;
  float num = m * d * d;
  float den = m;
#pragma unroll
  for (int off = 32; off > 0; off >>= 1) {
    num += __shfl_down(num, off);
    den += __shfl_down(den, off);
  }
  if ((tid & 63) == 0) {
    unsafeAtomicAdd(&accum[0], num);
    unsafeAtomicAdd(&accum[1], den);
  }
}

__global__ void k_loss(const float* __restrict__ accum, float* __restrict__ out_loss) {
  if (threadIdx.x == 0) out_loss[0] = accum[0] / (accum[1] + 1e-8f);
}

// ---------------- launch ----------------
extern "C" void kernel_launch(void* const* d_in, const int* in_sizes, int n_in,
                              void* d_out, int out_size, void* d_ws, size_t ws_size,
                              hipStream_t stream) {
  const float* x    = (const float*)d_in[0];
  const int*   ei   = (const int*)d_in[1];      // (2, E): row = ei, col = ei + E_
  const float* mask = (const float*)d_in[2];
  const float* W1 = (const float*)d_in[3];
  const float* b1 = (const float*)d_in[4];
  const float* W2 = (const float*)d_in[5];
  const float* b2 = (const float*)d_in[6];
  const float* WihF = (const float*)d_in[7];
  const float* WhhF = (const float*)d_in[8];
  const float* bihF = (const float*)d_in[9];
  const float* bhhF = (const float*)d_in[10];
  const float* WihB = (const float*)d_in[11];
  const float* WhhB = (const float*)d_in[12];
  const float* bihB = (const float*)d_in[13];
  const float* bhhB = (const float*)d_in[14];
  const float* Wd = (const float*)d_in[15];
  const float* bd = (const float*)d_in[16];
  float* out = (float*)d_out;

  char* ws = (char*)d_ws;
  float* dinv  = (float*)ws; ws += (size_t)NN_ * 4;
  float* accum = (float*)ws; ws += 256;
  float* bufA  = (float*)ws; ws += (size_t)NN_ * 64 * 4;
  float* bufB  = (float*)ws; ws += (size_t)NN_ * 64 * 4;
  float* bufC  = (float*)ws; ws += (size_t)NN_ * 64 * 4;
  float* y     = (float*)ws; ws += (size_t)NN_ * 128 * 4;

  // degrees (with self loop) -> dinv
  k_init<<<NN_ / 256, 256, 0, stream>>>(dinv, accum);
  k_deg<<<E_ / 256, 256, 0, stream>>>(ei + E_, dinv);
  k_dinv<<<NN_ / 256, 256, 0, stream>>>(dinv);

  // GCN layer 1: xw1 -> bufA, agg1 (self-loop init) -> bufB   (raw, no bias yet)
  k_gemm<FIN_, false><<<NN_ / 4, 256, 0, stream>>>(x, W1, nullptr, dinv, bufA, bufB);
  k_scatter<<<E_ / 4, 256, 0, stream>>>(ei, ei + E_, dinv, bufA, bufB);

  // GCN layer 2: relu(bufB + b1) fused on read; xw2 -> bufC, agg2 -> bufA
  k_gemm<64, true><<<NN_ / 4, 256, 0, stream>>>(bufB, W2, b1, dinv, bufC, bufA);
  k_scatter<<<E_ / 4, 256, 0, stream>>>(ei, ei + E_, dinv, bufC, bufA);

  // bidirectional LSTM (relu(bufA + b2) fused at staging): 128 persistent blocks
  k_lstm<<<128, 256, 0, stream>>>(bufA, b2, WihF, WhhF, bihF, bhhF,
                                  WihB, WhhB, bihB, bhhB, y);

  // decoder + loss
  k_decoder<<<NN_ / 16, 256, 0, stream>>>(y, x, mask, Wd, bd, out, accum);
  k_loss<<<1, 64, 0, stream>>>(accum, out + (size_t)NN_ * FIN_);
}

// Round 4
// 3414.974 us; speedup vs baseline: 1.3676x; 1.2274x over previous
//
#include <hip/hip_runtime.h>

#define NN_ 131072      // T*N
#define T_ 64
#define N_ 2048
#define E_ 2097152
#define FIN_ 16

typedef unsigned short ushort_t;
typedef unsigned int uint_t;

// LDS-only barrier (memory clobber: correctness-first; vmem ops are batched so
// any conservative vmcnt drain amortizes).
#define LBAR() asm volatile("s_waitcnt lgkmcnt(0)\n\ts_barrier" ::: "memory")

__device__ __forceinline__ float bf2f(ushort_t u) {
  return __uint_as_float(((uint_t)u) << 16);
}
__device__ __forceinline__ ushort_t f2bf(float f) {
  uint_t b = __float_as_uint(f);
  b += 0x7fffu + ((b >> 16) & 1u);   // round-to-nearest-even
  return (ushort_t)(b >> 16);
}

// ---------------- init: deg = 1 (self loop), accum = 0 ----------------
__global__ void k_init(float* __restrict__ deg, float* __restrict__ accum) {
  int idx = blockIdx.x * 256 + threadIdx.x;
  if (idx < NN_) deg[idx] = 1.0f;
  if (idx < 2) accum[idx] = 0.0f;
}

__global__ void k_deg(const int* __restrict__ col, float* __restrict__ deg) {
  int e = blockIdx.x * 256 + threadIdx.x;
  if (e < E_) unsafeAtomicAdd(&deg[col[e]], 1.0f);
}

__global__ void k_dinv(float* __restrict__ deg) {
  int v = blockIdx.x * 256 + threadIdx.x;
  if (v < NN_) deg[v] = rsqrtf(deg[v]);
}

// ---------------- GEMM (NN x K) @ (K x 64), fused self-loop agg init ----------
// Optionally applies relu(x + bin) while staging. agg may alias X (in-place):
// all reads of a block's rows complete (into LDS) before its writes.
template <int K, bool RELU_IN>
__global__ void k_gemm(const float* __restrict__ X, const float* __restrict__ W,
                       const float* __restrict__ bin, const float* __restrict__ dinv,
                       float* __restrict__ xw, float* __restrict__ agg) {
  __shared__ float xs[4 * K];
  const int tid = threadIdx.x;
  const int v0 = blockIdx.x * 4;
  for (int t = tid; t < 4 * K; t += 256) {
    float v = X[(size_t)v0 * K + t];
    if (RELU_IN) v = fmaxf(v + bin[t & (K - 1)], 0.f);
    xs[t] = v;
  }
  __syncthreads();
  const int v = v0 + (tid >> 6);
  const int j = tid & 63;
  const float* xr = &xs[(tid >> 6) * K];
  float acc = 0.f;
#pragma unroll
  for (int k = 0; k < K; ++k) acc = fmaf(xr[k], W[k * 64 + j], acc);
  float dv = dinv[v];
  size_t o = (size_t)v * 64 + j;
  xw[o] = acc;
  agg[o] = dv * dv * acc;   // self-loop contribution
}

// ---------------- edge scatter: agg[col] += dinv[row]*dinv[col]*xw[row] -------
__global__ void k_scatter(const int* __restrict__ row, const int* __restrict__ col,
                          const float* __restrict__ dinv, const float* __restrict__ xw,
                          float* __restrict__ agg) {
  int e = blockIdx.x * 4 + (threadIdx.x >> 6);
  int lane = threadIdx.x & 63;
  int r = row[e], c = col[e];
  float nrm = dinv[r] * dinv[c];
  float val = nrm * xw[(size_t)r * 64 + lane];
  unsafeAtomicAdd(&agg[(size_t)c * 64 + lane], val);
}

// ---------------- gate-preactivation GEMM -------------------------------------
// gx[dir][vrow][gate] = (bih+bhh)[gate] + relu(A[vrow]+b2) . Wih[gate]   (bf16)
// grid: 2*(NN_/64) blocks; 256 threads; thread t owns gate t's Wih row in regs.
__global__ __launch_bounds__(256) void k_gates(
    const float* __restrict__ A, const float* __restrict__ b2,
    const float* __restrict__ WihF, const float* __restrict__ bihF,
    const float* __restrict__ bhhF,
    const float* __restrict__ WihB, const float* __restrict__ bihB,
    const float* __restrict__ bhhB,
    ushort_t* __restrict__ gx) {
  const int dir = blockIdx.x >> 11;          // NN_/64 = 2048 blocks per dir
  const int v0 = (blockIdx.x & 2047) * 64;
  const float* Wih = dir ? WihB : WihF;
  const float* bih = dir ? bihB : bihF;
  const float* bhh = dir ? bhhB : bhhF;
  const int t = threadIdx.x;

  float w[64];
#pragma unroll
  for (int k = 0; k < 64; k += 4)
    *reinterpret_cast<float4*>(&w[k]) = *reinterpret_cast<const float4*>(&Wih[t * 64 + k]);
  const float bias = bih[t] + bhh[t];

  __shared__ float xs[64 * 64];
#pragma unroll
  for (int u = 0; u < 16; ++u) {
    int idx = u * 256 + t;
    xs[idx] = fmaxf(A[(size_t)v0 * 64 + idx] + b2[idx & 63], 0.f);
  }
  __syncthreads();

  ushort_t* gp = gx + ((size_t)(dir ? NN_ : 0) + v0) * 256 + t;
  for (int r = 0; r < 64; ++r) {
    const float* xr = &xs[r * 64];
    float a0 = 0.f, a1 = 0.f, a2 = 0.f, a3 = 0.f;
#pragma unroll
    for (int k = 0; k < 64; k += 16) {
      float4 x0 = *reinterpret_cast<const float4*>(&xr[k]);
      float4 x1 = *reinterpret_cast<const float4*>(&xr[k + 4]);
      float4 x2 = *reinterpret_cast<const float4*>(&xr[k + 8]);
      float4 x3 = *reinterpret_cast<const float4*>(&xr[k + 12]);
      a0 = fmaf(x0.x, w[k+0], a0);  a0 = fmaf(x0.y, w[k+1], a0);
      a0 = fmaf(x0.z, w[k+2], a0);  a0 = fmaf(x0.w, w[k+3], a0);
      a1 = fmaf(x1.x, w[k+4], a1);  a1 = fmaf(x1.y, w[k+5], a1);
      a1 = fmaf(x1.z, w[k+6], a1);  a1 = fmaf(x1.w, w[k+7], a1);
      a2 = fmaf(x2.x, w[k+8], a2);  a2 = fmaf(x2.y, w[k+9], a2);
      a2 = fmaf(x2.z, w[k+10], a2); a2 = fmaf(x2.w, w[k+11], a2);
      a3 = fmaf(x3.x, w[k+12], a3); a3 = fmaf(x3.y, w[k+13], a3);
      a3 = fmaf(x3.z, w[k+14], a3); a3 = fmaf(x3.w, w[k+15], a3);
    }
    gp[(size_t)r * 256] = f2bf(bias + (a0 + a1) + (a2 + a3));
  }
}

// ---------------- persistent bidirectional LSTM, precomputed gates ------------
// 128 blocks (b = blk&63, dir = blk>>6), 256 threads. ONE barrier/step:
// per-wave private hbuf (redundant activation, identical across waves),
// parity-double-buffered gbuf for the single cross-wave dependency.
__global__ __launch_bounds__(256) void k_lstm2(
    const ushort_t* __restrict__ gx,
    const float* __restrict__ WhhF, const float* __restrict__ WhhB,
    float* __restrict__ y) {
  const int b   = blockIdx.x & 63;
  const int dir = blockIdx.x >> 6;
  const int tid = threadIdx.x;
  const int w   = tid >> 6;
  const int l   = tid & 63;
  const float* Whh = dir ? WhhB : WhhF;

  float whh[64];
#pragma unroll
  for (int k = 0; k < 64; k += 4)
    *reinterpret_cast<float4*>(&whh[k]) = *reinterpret_cast<const float4*>(&Whh[tid * 64 + k]);

  __shared__ __align__(16) float hb[4][64];
  __shared__ float gb[2][256];
  hb[w][l] = 0.f;                    // each wave inits its own copy (in-order DS)
  float c = 0.f;

  const long stride = dir ? -256 : 256;
  const long ystr   = dir ? -128 : 128;
  const int s0 = dir ? N_ - 1 : 0;
  const ushort_t* p = gx + ((size_t)dir * NN_ + (size_t)b * N_ + s0) * 256 + tid;
  float* yp = y + ((size_t)b * N_ + s0) * 128 + (size_t)dir * 64 + l;

  float zc[8], zn[8];
#pragma unroll
  for (int i = 0; i < 8; ++i) zc[i] = bf2f(p[i * stride]);
  p += 8 * stride;

  const float* hrow = hb[w];

  for (int g = 0; g < N_ / 8; ++g) {
    if (g != N_ / 8 - 1) {
#pragma unroll
      for (int i = 0; i < 8; ++i) zn[i] = bf2f(p[i * stride]);
    }
    p += 8 * stride;
    float yv[8];
#pragma unroll
    for (int i = 0; i < 8; ++i) {
      const int par = i & 1;
      // ---- h-projection: 64 FMAs against own wave's hbuf (broadcast reads)
      float a0 = zc[i], a1 = 0.f, a2 = 0.f, a3 = 0.f;
#pragma unroll
      for (int k = 0; k < 64; k += 16) {
        float4 h0 = *reinterpret_cast<const float4*>(&hrow[k]);
        float4 h1 = *reinterpret_cast<const float4*>(&hrow[k + 4]);
        float4 h2 = *reinterpret_cast<const float4*>(&hrow[k + 8]);
        float4 h3 = *reinterpret_cast<const float4*>(&hrow[k + 12]);
        a0 = fmaf(h0.x, whh[k+0], a0);  a0 = fmaf(h0.y, whh[k+1], a0);
        a0 = fmaf(h0.z, whh[k+2], a0);  a0 = fmaf(h0.w, whh[k+3], a0);
        a1 = fmaf(h1.x, whh[k+4], a1);  a1 = fmaf(h1.y, whh[k+5], a1);
        a1 = fmaf(h1.z, whh[k+6], a1);  a1 = fmaf(h1.w, whh[k+7], a1);
        a2 = fmaf(h2.x, whh[k+8], a2);  a2 = fmaf(h2.y, whh[k+9], a2);
        a2 = fmaf(h2.z, whh[k+10], a2); a2 = fmaf(h2.w, whh[k+11], a2);
        a3 = fmaf(h3.x, whh[k+12], a3); a3 = fmaf(h3.y, whh[k+13], a3);
        a3 = fmaf(h3.z, whh[k+14], a3); a3 = fmaf(h3.w, whh[k+15], a3);
      }
      gb[par][tid] = (a0 + a1) + (a2 + a3);
      LBAR();                          // single barrier: publish all 256 gates
      // ---- redundant activation on every wave (identical FP -> identical c,h)
      float gi = gb[par][l], gf = gb[par][64 + l];
      float gg = gb[par][128 + l], go = gb[par][192 + l];
      float si_ = __fdividef(1.f, 1.f + __expf(-gi));
      float sf  = __fdividef(1.f, 1.f + __expf(-gf));
      float so  = __fdividef(1.f, 1.f + __expf(-go));
      float tg  = 1.f - __fdividef(2.f, __expf(2.f * gg) + 1.f);
      c = sf * c + si_ * tg;
      float tc = 1.f - __fdividef(2.f, __expf(2.f * c) + 1.f);
      float hh = so * tc;
      hb[w][l] = hh;                   // own-wave copy; in-order DS, no barrier
      yv[i] = hh;
      // gb[par] next written 2 steps later, after an intervening barrier: safe.
    }
    if (w == 0) {
#pragma unroll
      for (int i = 0; i < 8; ++i) yp[(long)i * ystr] = yv[i];
    }
    yp += 8 * ystr;
#pragma unroll
    for (int i = 0; i < 8; ++i) zc[i] = zn[i];
  }
}

// ---------------- fallback persistent LSTM (round-3 version) ------------------
__global__ __launch_bounds__(256) void k_lstm(
    const float* __restrict__ h2raw, const float* __restrict__ b2,
    const float* __restrict__ WihF, const float* __restrict__ WhhF,
    const float* __restrict__ bihF, const float* __restrict__ bhhF,
    const float* __restrict__ WihB, const float* __restrict__ WhhB,
    const float* __restrict__ bihB, const float* __restrict__ bhhB,
    float* __restrict__ y) {
  const int b   = blockIdx.x & 63;
  const int dir = blockIdx.x >> 6;
  const float* Wih = dir ? WihB : WihF;
  const float* Whh = dir ? WhhB : WhhF;
  const float* bih = dir ? bihB : bihF;
  const float* bhh = dir ? bhhB : bhhF;
  const int j = threadIdx.x;

  float wih[64], whh[64];
#pragma unroll
  for (int k = 0; k < 64; k += 4) {
    *reinterpret_cast<float4*>(&wih[k]) = *reinterpret_cast<const float4*>(&Wih[j * 64 + k]);
    *reinterpret_cast<float4*>(&whh[k]) = *reinterpret_cast<const float4*>(&Whh[j * 64 + k]);
  }
  const float bias = bih[j] + bhh[j];
  const float b2j = (j < 64) ? b2[j] : 0.f;

  __shared__ __align__(16) float xbuf[64];
  __shared__ __align__(16) float hbuf[64];
  __shared__ float gbuf[256];
  float c = 0.f;
  if (j < 64) hbuf[j] = 0.f;

  float xc = 0.f, xn = 0.f;
  if (j < 64) {
    const int s0 = dir ? N_ - 1 : 0;
    const int s1 = dir ? N_ - 2 : 1;
    xc = h2raw[((size_t)b * N_ + s0) * 64 + j];
    xn = h2raw[((size_t)b * N_ + s1) * 64 + j];
  }

  for (int si = 0; si < N_; ++si) {
    const int s = dir ? (N_ - 1 - si) : si;
    const size_t vrow = (size_t)b * N_ + s;
    if (j < 64) xbuf[j] = fmaxf(xc + b2j, 0.f);
    LBAR();

    float xp = 0.f;
    {
      int si2 = si + 2; if (si2 >= N_) si2 = N_ - 1;
      const int s2 = dir ? (N_ - 1 - si2) : si2;
      if (j < 64) xp = h2raw[((size_t)b * N_ + s2) * 64 + j];
    }

    float a0 = 0.f, a1 = 0.f, a2 = 0.f, a3 = 0.f;
#pragma unroll
    for (int k = 0; k < 64; k += 16) {
      float4 xv0 = *reinterpret_cast<const float4*>(&xbuf[k]);
      float4 hv0 = *reinterpret_cast<const float4*>(&hbuf[k]);
      a0 = fmaf(xv0.x, wih[k+0], a0); a0 = fmaf(hv0.x, whh[k+0], a0);
      a0 = fmaf(xv0.y, wih[k+1], a0); a0 = fmaf(hv0.y, whh[k+1], a0);
      a0 = fmaf(xv0.z, wih[k+2], a0); a0 = fmaf(hv0.z, whh[k+2], a0);
      a0 = fmaf(xv0.w, wih[k+3], a0); a0 = fmaf(hv0.w, whh[k+3], a0);
      float4 xv1 = *reinterpret_cast<const float4*>(&xbuf[k+4]);
      float4 hv1 = *reinterpret_cast<const float4*>(&hbuf[k+4]);
      a1 = fmaf(xv1.x, wih[k+4], a1); a1 = fmaf(hv1.x, whh[k+4], a1);
      a1 = fmaf(xv1.y, wih[k+5], a1); a1 = fmaf(hv1.y, whh[k+5], a1);
      a1 = fmaf(xv1.z, wih[k+6], a1); a1 = fmaf(hv1.z, whh[k+6], a1);
      a1 = fmaf(xv1.w, wih[k+7], a1); a1 = fmaf(hv1.w, whh[k+7], a1);
      float4 xv2 = *reinterpret_cast<const float4*>(&xbuf[k+8]);
      float4 hv2 = *reinterpret_cast<const float4*>(&hbuf[k+8]);
      a2 = fmaf(xv2.x, wih[k+8], a2); a2 = fmaf(hv2.x, whh[k+8], a2);
      a2 = fmaf(xv2.y, wih[k+9], a2); a2 = fmaf(hv2.y, whh[k+9], a2);
      a2 = fmaf(xv2.z, wih[k+10], a2); a2 = fmaf(hv2.z, whh[k+10], a2);
      a2 = fmaf(xv2.w, wih[k+11], a2); a2 = fmaf(hv2.w, whh[k+11], a2);
      float4 xv3 = *reinterpret_cast<const float4*>(&xbuf[k+12]);
      float4 hv3 = *reinterpret_cast<const float4*>(&hbuf[k+12]);
      a3 = fmaf(xv3.x, wih[k+12], a3); a3 = fmaf(hv3.x, whh[k+12], a3);
      a3 = fmaf(xv3.y, wih[k+13], a3); a3 = fmaf(hv3.y, whh[k+13], a3);
      a3 = fmaf(xv3.z, wih[k+14], a3); a3 = fmaf(hv3.z, whh[k+14], a3);
      a3 = fmaf(xv3.w, wih[k+15], a3); a3 = fmaf(hv3.w, whh[k+15], a3);
    }
    gbuf[j] = bias + (a0 + a1) + (a2 + a3);
    LBAR();

    if (j < 64) {
      float gi = gbuf[j], gf = gbuf[64 + j], gg = gbuf[128 + j], go = gbuf[192 + j];
      float si_ = __fdividef(1.f, 1.f + __expf(-gi));
      float sf  = __fdividef(1.f, 1.f + __expf(-gf));
      float so  = __fdividef(1.f, 1.f + __expf(-go));
      float tg  = 1.f - __fdividef(2.f, __expf(2.f * gg) + 1.f);
      c = sf * c + si_ * tg;
      float tc = 1.f - __fdividef(2.f, __expf(2.f * c) + 1.f);
      float hh = so * tc;
      hbuf[j] = hh;
      y[vrow * 128 + (size_t)dir * 64 + j] = hh;
    }
    xc = xn; xn = xp;
  }
}

// ---------------- decoder + masked MSE reduction ----------------
__global__ void k_decoder(const float* __restrict__ y, const float* __restrict__ x,
                          const float* __restrict__ mask, const float* __restrict__ Wd,
                          const float* __restrict__ bd, float* __restrict__ out,
                          float* __restrict__ accum) {
  int tid = threadIdx.x;
  size_t v = (size_t)blockIdx.x * 16 + (tid >> 4);
  int f = tid & 15;
  const float* yr = y + v * 128;
  float acc = bd[f];
#pragma unroll
  for (int jj = 0; jj < 128; jj += 4) {
    float4 yv = *reinterpret_cast<const float4*>(&yr[jj]);
    float4 wv = *reinterpret_cast<const float4*>(&Wd[f * 128 + jj]);
    acc = fmaf(yv.x, wv.x, acc); acc = fmaf(yv.y, wv.y, acc);
    acc = fmaf(yv.z, wv.z, acc); acc = fmaf(yv.w, wv.w, acc);
  }
  size_t o = v * 16 + f;
  float xv = x[o], m = mask[o];
  float d = acc - xv;
  out[o] = (m != 0.f) ? xv : acc;
  float num = m * d * d;
  float den = m;
#pragma unroll
  for (int off = 32; off > 0; off >>= 1) {
    num += __shfl_down(num, off);
    den += __shfl_down(den, off);
  }
  if ((tid & 63) == 0) {
    unsafeAtomicAdd(&accum[0], num);
    unsafeAtomicAdd(&accum[1], den);
  }
}

__global__ void k_loss(const float* __restrict__ accum, float* __restrict__ out_loss) {
  if (threadIdx.x == 0) out_loss[0] = accum[0] / (accum[1] + 1e-8f);
}

// ---------------- launch ----------------
extern "C" void kernel_launch(void* const* d_in, const int* in_sizes, int n_in,
                              void* d_out, int out_size, void* d_ws, size_t ws_size,
                              hipStream_t stream) {
  const float* x    = (const float*)d_in[0];
  const int*   ei   = (const int*)d_in[1];
  const float* mask = (const float*)d_in[2];
  const float* W1 = (const float*)d_in[3];
  const float* b1 = (const float*)d_in[4];
  const float* W2 = (const float*)d_in[5];
  const float* b2 = (const float*)d_in[6];
  const float* WihF = (const float*)d_in[7];
  const float* WhhF = (const float*)d_in[8];
  const float* bihF = (const float*)d_in[9];
  const float* bhhF = (const float*)d_in[10];
  const float* WihB = (const float*)d_in[11];
  const float* WhhB = (const float*)d_in[12];
  const float* bihB = (const float*)d_in[13];
  const float* bhhB = (const float*)d_in[14];
  const float* Wd = (const float*)d_in[15];
  const float* bd = (const float*)d_in[16];
  float* out = (float*)d_out;

  // layout: dinv | accum | Y(67M) | C(33.5M) | A(33.5M) | [gx = A..A+134M]
  float* dinv  = (float*)d_ws;
  float* accum = dinv + NN_;
  float* Y     = accum + 64;
  float* C     = Y + (size_t)NN_ * 128;
  float* A     = C + (size_t)NN_ * 64;
  ushort_t* gx = (ushort_t*)A;
  size_t need = ((char*)A - (char*)d_ws) + 2ull * NN_ * 256 * sizeof(ushort_t);
  bool use_gx = ws_size >= need;

  k_init<<<NN_ / 256, 256, 0, stream>>>(dinv, accum);
  k_deg<<<E_ / 256, 256, 0, stream>>>(ei + E_, dinv);
  k_dinv<<<NN_ / 256, 256, 0, stream>>>(dinv);

  // GCN layer 1: xw1 -> A, agg1 -> C
  k_gemm<FIN_, false><<<NN_ / 4, 256, 0, stream>>>(x, W1, nullptr, dinv, A, C);
  k_scatter<<<E_ / 4, 256, 0, stream>>>(ei, ei + E_, dinv, A, C);

  // GCN layer 2: reads C (relu(+b1) fused), xw2 -> A, agg2 -> C (in-place)
  k_gemm<64, true><<<NN_ / 4, 256, 0, stream>>>(C, W2, b1, dinv, A, C);
  k_scatter<<<E_ / 4, 256, 0, stream>>>(ei, ei + E_, dinv, A, C);

  if (use_gx) {
    k_gates<<<2 * (NN_ / 64), 256, 0, stream>>>(C, b2, WihF, bihF, bhhF,
                                                WihB, bihB, bhhB, gx);
    k_lstm2<<<128, 256, 0, stream>>>(gx, WhhF, WhhB, Y);
  } else {
    k_lstm<<<128, 256, 0, stream>>>(C, b2, WihF, WhhF, bihF, bhhF,
                                    WihB, WhhB, bihB, bhhB, Y);
  }

  k_decoder<<<NN_ / 16, 256, 0, stream>>>(Y, x, mask, Wd, bd, out, accum);
  k_loss<<<1, 64, 0, stream>>>(accum, out + (size_t)NN_ * FIN_);
}

// Round 5
// 3063.676 us; speedup vs baseline: 1.5244x; 1.1147x over previous
//
#include <hip/hip_runtime.h>

#define NN_ 131072      // T*N
#define T_ 64
#define N_ 2048
#define E_ 2097152
#define FIN_ 16

typedef unsigned short ushort_t;
typedef unsigned int uint_t;

// Old conservative barrier (memory clobber => compiler adds vmcnt(0) drain).
// Kept only for the fallback kernel.
#define LBAR() asm volatile("s_waitcnt lgkmcnt(0)\n\ts_barrier" ::: "memory")

// LDS-only barrier, m201/m214 pattern: publishes LDS writes across waves
// WITHOUT draining vmcnt (global prefetches / stores stay in flight).
// sched_barrier(0) pins machine-level placement (rule #18).
__device__ __forceinline__ void lbar2() {
  __builtin_amdgcn_sched_barrier(0);
  asm volatile("s_waitcnt lgkmcnt(0)");
  __builtin_amdgcn_s_barrier();
  __builtin_amdgcn_sched_barrier(0);
}

__device__ __forceinline__ float bf2f(ushort_t u) {
  return __uint_as_float(((uint_t)u) << 16);
}
__device__ __forceinline__ ushort_t f2bf(float f) {
  uint_t b = __float_as_uint(f);
  b += 0x7fffu + ((b >> 16) & 1u);   // round-to-nearest-even
  return (ushort_t)(b >> 16);
}

// ---------------- zero cnt + accum ----------------
__global__ void k_zero(uint_t* __restrict__ cnt, float* __restrict__ accum) {
  int i = blockIdx.x * 256 + threadIdx.x;
  if (i < NN_) cnt[i] = 0u;
  if (i < 2) accum[i] = 0.f;
}

// ---------------- histogram of col ----------------
__global__ void k_hist(const int* __restrict__ col, uint_t* __restrict__ cnt) {
  int e = blockIdx.x * 256 + threadIdx.x;
  atomicAdd(&cnt[col[e]], 1u);
}

// ---------------- dinv from counts (+1 self loop) ----------------
__global__ void k_dinvc(const uint_t* __restrict__ cnt, float* __restrict__ dinv) {
  int v = blockIdx.x * 256 + threadIdx.x;
  dinv[v] = rsqrtf((float)cnt[v] + 1.f);
}

// ---------------- per-256-chunk sums ----------------
__global__ void k_bsum(const uint_t* __restrict__ cnt, uint_t* __restrict__ bsum) {
  int t = threadIdx.x;
  uint_t v = cnt[blockIdx.x * 256 + t];
  for (int off = 32; off; off >>= 1) v += __shfl_down(v, off);
  __shared__ uint_t s4[4];
  if ((t & 63) == 0) s4[t >> 6] = v;
  __syncthreads();
  if (t == 0) bsum[blockIdx.x] = s4[0] + s4[1] + s4[2] + s4[3];
}

// ---------------- exclusive scan of 512 chunk sums (1 block) ----------------
__global__ void k_scan512(uint_t* __restrict__ bsum) {
  __shared__ uint_t sd[512];
  int t = threadIdx.x;
  uint_t v = bsum[t];
  sd[t] = v;
  __syncthreads();
  for (int off = 1; off < 512; off <<= 1) {
    uint_t x = (t >= off) ? sd[t - off] : 0u;
    __syncthreads();
    sd[t] += x;
    __syncthreads();
  }
  bsum[t] = sd[t] - v;   // exclusive
}

// ---------------- per-chunk exclusive scan + chunk offset -> start, cursor ----
__global__ void k_scanadd(const uint_t* __restrict__ cnt, const uint_t* __restrict__ bsum,
                          uint_t* __restrict__ start, uint_t* __restrict__ cursor) {
  int t = threadIdx.x;
  int i = blockIdx.x * 256 + t;
  uint_t v = cnt[i];
  __shared__ uint_t sd[256];
  sd[t] = v;
  __syncthreads();
  for (int off = 1; off < 256; off <<= 1) {
    uint_t x = (t >= off) ? sd[t - off] : 0u;
    __syncthreads();
    sd[t] += x;
    __syncthreads();
  }
  uint_t excl = sd[t] - v + bsum[blockIdx.x];
  start[i] = excl;
  cursor[i] = excl;
  if (i == NN_ - 1) start[NN_] = E_;
}

// ---------------- counting-sort placement: srow grouped by col ----------------
__global__ void k_place(const int* __restrict__ row, const int* __restrict__ col,
                        uint_t* __restrict__ cursor, int* __restrict__ srow) {
  int e = blockIdx.x * 256 + threadIdx.x;
  int c = col[e];
  uint_t pos = atomicAdd(&cursor[c], 1u);
  srow[pos] = row[e];
}

// ---------------- GEMM (NN x K) @ (K x 64), writes dinv-prescaled rows -------
// xws[v] = dinv[v] * (relu_in? relu(X[v]+bin) : X[v]) @ W
template <int K, bool RELU_IN>
__global__ void k_gemm(const float* __restrict__ X, const float* __restrict__ W,
                       const float* __restrict__ bin, const float* __restrict__ dinv,
                       float* __restrict__ xws) {
  __shared__ float xs[4 * K];
  const int tid = threadIdx.x;
  const int v0 = blockIdx.x * 4;
  for (int t = tid; t < 4 * K; t += 256) {
    float v = X[(size_t)v0 * K + t];
    if (RELU_IN) v = fmaxf(v + bin[t & (K - 1)], 0.f);
    xs[t] = v;
  }
  __syncthreads();
  const int v = v0 + (tid >> 6);
  const int j = tid & 63;
  const float* xr = &xs[(tid >> 6) * K];
  float acc = 0.f;
#pragma unroll
  for (int k = 0; k < K; ++k) acc = fmaf(xr[k], W[k * 64 + j], acc);
  xws[(size_t)v * 64 + j] = dinv[v] * acc;
}

// ---------------- column-gather aggregation (no atomics) ----------------------
// agg[c] = dinv[c] * (xws[c] + sum_{edges r->c} xws[r])
// one wave per col, lane = feature.
__global__ void k_colagg(const int* __restrict__ srow, const uint_t* __restrict__ start,
                         const float* __restrict__ dinv, const float* __restrict__ xws,
                         float* __restrict__ agg) {
  int c = blockIdx.x * 4 + (threadIdx.x >> 6);
  int lane = threadIdx.x & 63;
  uint_t s = start[c], e = start[c + 1];
  float acc = xws[(size_t)c * 64 + lane];      // self loop: dinv[c]*xw[c]
  for (uint_t i = s; i < e; ++i) {
    int r = srow[i];
    acc += xws[(size_t)r * 64 + lane];
  }
  agg[(size_t)c * 64 + lane] = dinv[c] * acc;
}

// ---------------- gate-preactivation GEMM (bf16 out) --------------------------
__global__ __launch_bounds__(256) void k_gates(
    const float* __restrict__ A, const float* __restrict__ b2,
    const float* __restrict__ WihF, const float* __restrict__ bihF,
    const float* __restrict__ bhhF,
    const float* __restrict__ WihB, const float* __restrict__ bihB,
    const float* __restrict__ bhhB,
    ushort_t* __restrict__ gx) {
  const int dir = blockIdx.x >> 11;
  const int v0 = (blockIdx.x & 2047) * 64;
  const float* Wih = dir ? WihB : WihF;
  const float* bih = dir ? bihB : bihF;
  const float* bhh = dir ? bhhB : bhhF;
  const int t = threadIdx.x;

  float w[64];
#pragma unroll
  for (int k = 0; k < 64; k += 4)
    *reinterpret_cast<float4*>(&w[k]) = *reinterpret_cast<const float4*>(&Wih[t * 64 + k]);
  const float bias = bih[t] + bhh[t];

  __shared__ float xs[64 * 64];
#pragma unroll
  for (int u = 0; u < 16; ++u) {
    int idx = u * 256 + t;
    xs[idx] = fmaxf(A[(size_t)v0 * 64 + idx] + b2[idx & 63], 0.f);
  }
  __syncthreads();

  ushort_t* gp = gx + ((size_t)(dir ? NN_ : 0) + v0) * 256 + t;
  for (int r = 0; r < 64; ++r) {
    const float* xr = &xs[r * 64];
    float a0 = 0.f, a1 = 0.f, a2 = 0.f, a3 = 0.f;
#pragma unroll
    for (int k = 0; k < 64; k += 16) {
      float4 x0 = *reinterpret_cast<const float4*>(&xr[k]);
      float4 x1 = *reinterpret_cast<const float4*>(&xr[k + 4]);
      float4 x2 = *reinterpret_cast<const float4*>(&xr[k + 8]);
      float4 x3 = *reinterpret_cast<const float4*>(&xr[k + 12]);
      a0 = fmaf(x0.x, w[k+0], a0);  a0 = fmaf(x0.y, w[k+1], a0);
      a0 = fmaf(x0.z, w[k+2], a0);  a0 = fmaf(x0.w, w[k+3], a0);
      a1 = fmaf(x1.x, w[k+4], a1);  a1 = fmaf(x1.y, w[k+5], a1);
      a1 = fmaf(x1.z, w[k+6], a1);  a1 = fmaf(x1.w, w[k+7], a1);
      a2 = fmaf(x2.x, w[k+8], a2);  a2 = fmaf(x2.y, w[k+9], a2);
      a2 = fmaf(x2.z, w[k+10], a2); a2 = fmaf(x2.w, w[k+11], a2);
      a3 = fmaf(x3.x, w[k+12], a3); a3 = fmaf(x3.y, w[k+13], a3);
      a3 = fmaf(x3.z, w[k+14], a3); a3 = fmaf(x3.w, w[k+15], a3);
    }
    gp[(size_t)r * 256] = f2bf(bias + (a0 + a1) + (a2 + a3));
  }
}

// ---------------- persistent bidirectional LSTM, precomputed gates ------------
__global__ __launch_bounds__(256) void k_lstm2(
    const ushort_t* __restrict__ gx,
    const float* __restrict__ WhhF, const float* __restrict__ WhhB,
    float* __restrict__ y) {
  const int b   = blockIdx.x & 63;
  const int dir = blockIdx.x >> 6;
  const int tid = threadIdx.x;
  const int w   = tid >> 6;
  const int l   = tid & 63;
  const float* Whh = dir ? WhhB : WhhF;

  float whh[64];
#pragma unroll
  for (int k = 0; k < 64; k += 4)
    *reinterpret_cast<float4*>(&whh[k]) = *reinterpret_cast<const float4*>(&Whh[tid * 64 + k]);

  __shared__ __align__(16) float hb[4][64];
  __shared__ float gb[2][256];
  hb[w][l] = 0.f;                    // own-wave copy (in-order DS)
  float c = 0.f;

  const long stride = dir ? -256 : 256;
  const long ystr   = dir ? -128 : 128;
  const int s0 = dir ? N_ - 1 : 0;
  const ushort_t* p = gx + ((size_t)dir * NN_ + (size_t)b * N_ + s0) * 256 + tid;
  float* yp = y + ((size_t)b * N_ + s0) * 128 + (size_t)dir * 64 + l;

  float zc[8], zn[8];
#pragma unroll
  for (int i = 0; i < 8; ++i) zc[i] = bf2f(p[i * stride]);
  p += 8 * stride;

  const float* hrow = hb[w];

  for (int g = 0; g < N_ / 8; ++g) {
    if (g != N_ / 8 - 1) {
#pragma unroll
      for (int i = 0; i < 8; ++i) zn[i] = bf2f(p[i * stride]);
    }
    p += 8 * stride;
    float yv[8];
#pragma unroll
    for (int i = 0; i < 8; ++i) {
      const int par = i & 1;
      float a0 = zc[i], a1 = 0.f, a2 = 0.f, a3 = 0.f;
#pragma unroll
      for (int k = 0; k < 64; k += 16) {
        float4 h0 = *reinterpret_cast<const float4*>(&hrow[k]);
        float4 h1 = *reinterpret_cast<const float4*>(&hrow[k + 4]);
        float4 h2 = *reinterpret_cast<const float4*>(&hrow[k + 8]);
        float4 h3 = *reinterpret_cast<const float4*>(&hrow[k + 12]);
        a0 = fmaf(h0.x, whh[k+0], a0);  a0 = fmaf(h0.y, whh[k+1], a0);
        a0 = fmaf(h0.z, whh[k+2], a0);  a0 = fmaf(h0.w, whh[k+3], a0);
        a1 = fmaf(h1.x, whh[k+4], a1);  a1 = fmaf(h1.y, whh[k+5], a1);
        a1 = fmaf(h1.z, whh[k+6], a1);  a1 = fmaf(h1.w, whh[k+7], a1);
        a2 = fmaf(h2.x, whh[k+8], a2);  a2 = fmaf(h2.y, whh[k+9], a2);
        a2 = fmaf(h2.z, whh[k+10], a2); a2 = fmaf(h2.w, whh[k+11], a2);
        a3 = fmaf(h3.x, whh[k+12], a3); a3 = fmaf(h3.y, whh[k+13], a3);
        a3 = fmaf(h3.z, whh[k+14], a3); a3 = fmaf(h3.w, whh[k+15], a3);
      }
      gb[par][tid] = (a0 + a1) + (a2 + a3);
      lbar2();                         // single barrier: publish all 256 gates
      float gi = gb[par][l], gf = gb[par][64 + l];
      float gg = gb[par][128 + l], go = gb[par][192 + l];
      float si_ = __fdividef(1.f, 1.f + __expf(-gi));
      float sf  = __fdividef(1.f, 1.f + __expf(-gf));
      float so  = __fdividef(1.f, 1.f + __expf(-go));
      float tg  = 1.f - __fdividef(2.f, __expf(2.f * gg) + 1.f);
      c = sf * c + si_ * tg;
      float tc = 1.f - __fdividef(2.f, __expf(2.f * c) + 1.f);
      float hh = so * tc;
      hb[w][l] = hh;                   // own-wave copy; no barrier needed
      yv[i] = hh;
      // gb[par] rewritten 2 steps later, after an intervening barrier: safe.
    }
    if (w == 0) {
#pragma unroll
      for (int i = 0; i < 8; ++i) yp[(long)i * ystr] = yv[i];
    }
    yp += 8 * ystr;
#pragma unroll
    for (int i = 0; i < 8; ++i) zc[i] = zn[i];
  }
}

// ---------------- fallback persistent LSTM (round-3 version, safe path) -------
__global__ __launch_bounds__(256) void k_lstm(
    const float* __restrict__ h2raw, const float* __restrict__ b2,
    const float* __restrict__ WihF, const float* __restrict__ WhhF,
    const float* __restrict__ bihF, const float* __restrict__ bhhF,
    const float* __restrict__ WihB, const float* __restrict__ WhhB,
    const float* __restrict__ bihB, const float* __restrict__ bhhB,
    float* __restrict__ y) {
  const int b   = blockIdx.x & 63;
  const int dir = blockIdx.x >> 6;
  const float* Wih = dir ? WihB : WihF;
  const float* Whh = dir ? WhhB : WhhF;
  const float* bih = dir ? bihB : bihF;
  const float* bhh = dir ? bhhB : bhhF;
  const int j = threadIdx.x;

  float wih[64], whh[64];
#pragma unroll
  for (int k = 0; k < 64; k += 4) {
    *reinterpret_cast<float4*>(&wih[k]) = *reinterpret_cast<const float4*>(&Wih[j * 64 + k]);
    *reinterpret_cast<float4*>(&whh[k]) = *reinterpret_cast<const float4*>(&Whh[j * 64 + k]);
  }
  const float bias = bih[j] + bhh[j];
  const float b2j = (j < 64) ? b2[j] : 0.f;

  __shared__ __align__(16) float xbuf[64];
  __shared__ __align__(16) float hbuf[64];
  __shared__ float gbuf[256];
  float c = 0.f;
  if (j < 64) hbuf[j] = 0.f;

  float xc = 0.f, xn = 0.f;
  if (j < 64) {
    const int s0 = dir ? N_ - 1 : 0;
    const int s1 = dir ? N_ - 2 : 1;
    xc = h2raw[((size_t)b * N_ + s0) * 64 + j];
    xn = h2raw[((size_t)b * N_ + s1) * 64 + j];
  }

  for (int si = 0; si < N_; ++si) {
    const int s = dir ? (N_ - 1 - si) : si;
    const size_t vrow = (size_t)b * N_ + s;
    if (j < 64) xbuf[j] = fmaxf(xc + b2j, 0.f);
    LBAR();

    float xp = 0.f;
    {
      int si2 = si + 2; if (si2 >= N_) si2 = N_ - 1;
      const int s2 = dir ? (N_ - 1 - si2) : si2;
      if (j < 64) xp = h2raw[((size_t)b * N_ + s2) * 64 + j];
    }

    float a0 = 0.f, a1 = 0.f, a2 = 0.f, a3 = 0.f;
#pragma unroll
    for (int k = 0; k < 64; k += 16) {
      float4 xv0 = *reinterpret_cast<const float4*>(&xbuf[k]);
      float4 hv0 = *reinterpret_cast<const float4*>(&hbuf[k]);
      a0 = fmaf(xv0.x, wih[k+0], a0); a0 = fmaf(hv0.x, whh[k+0], a0);
      a0 = fmaf(xv0.y, wih[k+1], a0); a0 = fmaf(hv0.y, whh[k+1], a0);
      a0 = fmaf(xv0.z, wih[k+2], a0); a0 = fmaf(hv0.z, whh[k+2], a0);
      a0 = fmaf(xv0.w, wih[k+3], a0); a0 = fmaf(hv0.w, whh[k+3], a0);
      float4 xv1 = *reinterpret_cast<const float4*>(&xbuf[k+4]);
      float4 hv1 = *reinterpret_cast<const float4*>(&hbuf[k+4]);
      a1 = fmaf(xv1.x, wih[k+4], a1); a1 = fmaf(hv1.x, whh[k+4], a1);
      a1 = fmaf(xv1.y, wih[k+5], a1); a1 = fmaf(hv1.y, whh[k+5], a1);
      a1 = fmaf(xv1.z, wih[k+6], a1); a1 = fmaf(hv1.z, whh[k+6], a1);
      a1 = fmaf(xv1.w, wih[k+7], a1); a1 = fmaf(hv1.w, whh[k+7], a1);
      float4 xv2 = *reinterpret_cast<const float4*>(&xbuf[k+8]);
      float4 hv2 = *reinterpret_cast<const float4*>(&hbuf[k+8]);
      a2 = fmaf(xv2.x, wih[k+8], a2); a2 = fmaf(hv2.x, whh[k+8], a2);
      a2 = fmaf(xv2.y, wih[k+9], a2); a2 = fmaf(hv2.y, whh[k+9], a2);
      a2 = fmaf(xv2.z, wih[k+10], a2); a2 = fmaf(hv2.z, whh[k+10], a2);
      a2 = fmaf(xv2.w, wih[k+11], a2); a2 = fmaf(hv2.w, whh[k+11], a2);
      float4 xv3 = *reinterpret_cast<const float4*>(&xbuf[k+12]);
      float4 hv3 = *reinterpret_cast<const float4*>(&hbuf[k+12]);
      a3 = fmaf(xv3.x, wih[k+12], a3); a3 = fmaf(hv3.x, whh[k+12], a3);
      a3 = fmaf(xv3.y, wih[k+13], a3); a3 = fmaf(hv3.y, whh[k+13], a3);
      a3 = fmaf(xv3.z, wih[k+14], a3); a3 = fmaf(hv3.z, whh[k+14], a3);
      a3 = fmaf(xv3.w, wih[k+15], a3); a3 = fmaf(hv3.w, whh[k+15], a3);
    }
    gbuf[j] = bias + (a0 + a1) + (a2 + a3);
    LBAR();

    if (j < 64) {
      float gi = gbuf[j], gf = gbuf[64 + j], gg = gbuf[128 + j], go = gbuf[192 + j];
      float si_ = __fdividef(1.f, 1.f + __expf(-gi));
      float sf  = __fdividef(1.f, 1.f + __expf(-gf));
      float so  = __fdividef(1.f, 1.f + __expf(-go));
      float tg  = 1.f - __fdividef(2.f, __expf(2.f * gg) + 1.f);
      c = sf * c + si_ * tg;
      float tc = 1.f - __fdividef(2.f, __expf(2.f * c) + 1.f);
      float hh = so * tc;
      hbuf[j] = hh;
      y[vrow * 128 + (size_t)dir * 64 + j] = hh;
    }
    xc = xn; xn = xp;
  }
}

// ---------------- decoder + masked MSE reduction ----------------
__global__ void k_decoder(const float* __restrict__ y, const float* __restrict__ x,
                          const float* __restrict__ mask, const float* __restrict__ Wd,
                          const float* __restrict__ bd, float* __restrict__ out,
                          float* __restrict__ accum) {
  int tid = threadIdx.x;
  size_t v = (size_t)blockIdx.x * 16 + (tid >> 4);
  int f = tid & 15;
  const float* yr = y + v * 128;
  float acc = bd[f];
#pragma unroll
  for (int jj = 0; jj < 128; jj += 4) {
    float4 yv = *reinterpret_cast<const float4*>(&yr[jj]);
    float4 wv = *reinterpret_cast<const float4*>(&Wd[f * 128 + jj]);
    acc = fmaf(yv.x, wv.x, acc); acc = fmaf(yv.y, wv.y, acc);
    acc = fmaf(yv.z, wv.z, acc); acc = fmaf(yv.w, wv.w, acc);
  }
  size_t o = v * 16 + f;
  float xv = x[o], m = mask[o];
  float d = acc - xv;
  out[o] = (m != 0.f) ? xv : acc;
  float num = m * d * d;
  float den = m;
#pragma unroll
  for (int off = 32; off > 0; off >>= 1) {
    num += __shfl_down(num, off);
    den += __shfl_down(den, off);
  }
  if ((tid & 63) == 0) {
    unsafeAtomicAdd(&accum[0], num);
    unsafeAtomicAdd(&accum[1], den);
  }
}

__global__ void k_loss(const float* __restrict__ accum, float* __restrict__ out_loss) {
  if (threadIdx.x == 0) out_loss[0] = accum[0] / (accum[1] + 1e-8f);
}

// ---------------- launch ----------------
extern "C" void kernel_launch(void* const* d_in, const int* in_sizes, int n_in,
                              void* d_out, int out_size, void* d_ws, size_t ws_size,
                              hipStream_t stream) {
  const float* x    = (const float*)d_in[0];
  const int*   ei   = (const int*)d_in[1];   // row = ei, col = ei + E_
  const float* mask = (const float*)d_in[2];
  const float* W1 = (const float*)d_in[3];
  const float* b1 = (const float*)d_in[4];
  const float* W2 = (const float*)d_in[5];
  const float* b2 = (const float*)d_in[6];
  const float* WihF = (const float*)d_in[7];
  const float* WhhF = (const float*)d_in[8];
  const float* bihF = (const float*)d_in[9];
  const float* bhhF = (const float*)d_in[10];
  const float* WihB = (const float*)d_in[11];
  const float* WhhB = (const float*)d_in[12];
  const float* bihB = (const float*)d_in[13];
  const float* bhhB = (const float*)d_in[14];
  const float* Wd = (const float*)d_in[15];
  const float* bd = (const float*)d_in[16];
  float* out = (float*)d_out;

  // layout: dinv | accum | Y(67M) | C(33.5M) | A(33.5M, gx overlays A +134M)
  float* dinv  = (float*)d_ws;
  float* accum = dinv + NN_;
  float* Y     = accum + 64;
  float* C     = Y + (size_t)NN_ * 128;
  float* A     = C + (size_t)NN_ * 64;
  ushort_t* gx = (ushort_t*)A;
  // sort scratch overlays Y (dead until k_lstm writes it)
  int*    srow   = (int*)Y;
  uint_t* cnt    = (uint_t*)(srow + E_);
  uint_t* start  = cnt + NN_;
  uint_t* cursor = start + NN_ + 1;
  uint_t* bsum   = cursor + NN_;

  size_t need = ((char*)A - (char*)d_ws) + 2ull * NN_ * 256 * sizeof(ushort_t);
  bool use_gx = ws_size >= need;

  // ---- degree + col-sort (replaces k_deg + atomic scatter prep) ----
  k_zero<<<NN_ / 256, 256, 0, stream>>>(cnt, accum);
  k_hist<<<E_ / 256, 256, 0, stream>>>(ei + E_, cnt);
  k_dinvc<<<NN_ / 256, 256, 0, stream>>>(cnt, dinv);
  k_bsum<<<512, 256, 0, stream>>>(cnt, bsum);
  k_scan512<<<1, 512, 0, stream>>>(bsum);
  k_scanadd<<<512, 256, 0, stream>>>(cnt, bsum, start, cursor);
  k_place<<<E_ / 256, 256, 0, stream>>>(ei, ei + E_, cursor, srow);

  // ---- GCN layer 1: xws1 -> A, agg1 -> C ----
  k_gemm<FIN_, false><<<NN_ / 4, 256, 0, stream>>>(x, W1, nullptr, dinv, A);
  k_colagg<<<NN_ / 4, 256, 0, stream>>>(srow, start, dinv, A, C);

  // ---- GCN layer 2: reads C (relu+b1 fused), xws2 -> A, agg2 -> C ----
  k_gemm<64, true><<<NN_ / 4, 256, 0, stream>>>(C, W2, b1, dinv, A);
  k_colagg<<<NN_ / 4, 256, 0, stream>>>(srow, start, dinv, A, C);

  if (use_gx) {
    k_gates<<<2 * (NN_ / 64), 256, 0, stream>>>(C, b2, WihF, bihF, bhhF,
                                                WihB, bihB, bhhB, gx);
    k_lstm2<<<128, 256, 0, stream>>>(gx, WhhF, WhhB, Y);
  } else {
    k_lstm<<<128, 256, 0, stream>>>(C, b2, WihF, WhhF, bihF, bhhF,
                                    WihB, WhhB, bihB, bhhB, Y);
  }

  k_decoder<<<NN_ / 16, 256, 0, stream>>>(Y, x, mask, Wd, bd, out, accum);
  k_loss<<<1, 64, 0, stream>>>(accum, out + (size_t)NN_ * FIN_);
}

// Round 7
// 3023.224 us; speedup vs baseline: 1.5448x; 1.0134x over previous
//
#include <hip/hip_runtime.h>

#define NN_ 131072      // T*N
#define T_ 64
#define N_ 2048
#define E_ 2097152
#define FIN_ 16

typedef unsigned short ushort_t;
typedef unsigned int uint_t;

// memory-clobber LDS barrier (fallback kernel only)
#define LBAR() asm volatile("s_waitcnt lgkmcnt(0)\n\ts_barrier" ::: "memory")

__device__ __forceinline__ float bf2f(ushort_t u) {
  return __uint_as_float(((uint_t)u) << 16);
}
__device__ __forceinline__ ushort_t f2bf(float f) {
  uint_t b = __float_as_uint(f);
  b += 0x7fffu + ((b >> 16) & 1u);   // round-to-nearest-even
  return (ushort_t)(b >> 16);
}

// ---------------- zero cnt + accum ----------------
__global__ void k_zero(uint_t* __restrict__ cnt, float* __restrict__ accum) {
  int i = blockIdx.x * 256 + threadIdx.x;
  if (i < NN_) cnt[i] = 0u;
  if (i < 2) accum[i] = 0.f;
}

// ---------------- histogram of col ----------------
__global__ void k_hist(const int* __restrict__ col, uint_t* __restrict__ cnt) {
  int e = blockIdx.x * 256 + threadIdx.x;
  atomicAdd(&cnt[col[e]], 1u);
}

// ---------------- dinv from counts (+1 self loop) ----------------
__global__ void k_dinvc(const uint_t* __restrict__ cnt, float* __restrict__ dinv) {
  int v = blockIdx.x * 256 + threadIdx.x;
  dinv[v] = rsqrtf((float)cnt[v] + 1.f);
}

// ---------------- per-256-chunk sums ----------------
__global__ void k_bsum(const uint_t* __restrict__ cnt, uint_t* __restrict__ bsum) {
  int t = threadIdx.x;
  uint_t v = cnt[blockIdx.x * 256 + t];
  for (int off = 32; off; off >>= 1) v += __shfl_down(v, off);
  __shared__ uint_t s4[4];
  if ((t & 63) == 0) s4[t >> 6] = v;
  __syncthreads();
  if (t == 0) bsum[blockIdx.x] = s4[0] + s4[1] + s4[2] + s4[3];
}

// ---------------- exclusive scan of 512 chunk sums (1 block) ----------------
__global__ void k_scan512(uint_t* __restrict__ bsum) {
  __shared__ uint_t sd[512];
  int t = threadIdx.x;
  uint_t v = bsum[t];
  sd[t] = v;
  __syncthreads();
  for (int off = 1; off < 512; off <<= 1) {
    uint_t x = (t >= off) ? sd[t - off] : 0u;
    __syncthreads();
    sd[t] += x;
    __syncthreads();
  }
  bsum[t] = sd[t] - v;   // exclusive
}

// ---------------- per-chunk exclusive scan + chunk offset ----------------
__global__ void k_scanadd(const uint_t* __restrict__ cnt, const uint_t* __restrict__ bsum,
                          uint_t* __restrict__ start, uint_t* __restrict__ cursor) {
  int t = threadIdx.x;
  int i = blockIdx.x * 256 + t;
  uint_t v = cnt[i];
  __shared__ uint_t sd[256];
  sd[t] = v;
  __syncthreads();
  for (int off = 1; off < 256; off <<= 1) {
    uint_t x = (t >= off) ? sd[t - off] : 0u;
    __syncthreads();
    sd[t] += x;
    __syncthreads();
  }
  uint_t excl = sd[t] - v + bsum[blockIdx.x];
  start[i] = excl;
  cursor[i] = excl;
  if (i == NN_ - 1) start[NN_] = E_;
}

// ---------------- counting-sort placement: srow grouped by col ----------------
__global__ void k_place(const int* __restrict__ row, const int* __restrict__ col,
                        uint_t* __restrict__ cursor, int* __restrict__ srow) {
  int e = blockIdx.x * 256 + threadIdx.x;
  int c = col[e];
  uint_t pos = atomicAdd(&cursor[c], 1u);
  srow[pos] = row[e];
}

// ---------------- GEMM (NN x K) @ (K x 64), writes dinv-prescaled rows -------
template <int K, bool RELU_IN>
__global__ void k_gemm(const float* __restrict__ X, const float* __restrict__ W,
                       const float* __restrict__ bin, const float* __restrict__ dinv,
                       float* __restrict__ xws) {
  __shared__ float xs[4 * K];
  const int tid = threadIdx.x;
  const int v0 = blockIdx.x * 4;
  for (int t = tid; t < 4 * K; t += 256) {
    float v = X[(size_t)v0 * K + t];
    if (RELU_IN) v = fmaxf(v + bin[t & (K - 1)], 0.f);
    xs[t] = v;
  }
  __syncthreads();
  const int v = v0 + (tid >> 6);
  const int j = tid & 63;
  const float* xr = &xs[(tid >> 6) * K];
  float acc = 0.f;
#pragma unroll
  for (int k = 0; k < K; ++k) acc = fmaf(xr[k], W[k * 64 + j], acc);
  xws[(size_t)v * 64 + j] = dinv[v] * acc;
}

// ---------------- column-gather aggregation (no atomics) ----------------------
__global__ void k_colagg(const int* __restrict__ srow, const uint_t* __restrict__ start,
                         const float* __restrict__ dinv, const float* __restrict__ xws,
                         float* __restrict__ agg) {
  int c = blockIdx.x * 4 + (threadIdx.x >> 6);
  int lane = threadIdx.x & 63;
  uint_t s = start[c], e = start[c + 1];
  float acc = xws[(size_t)c * 64 + lane];      // self loop
  for (uint_t i = s; i < e; ++i) {
    int r = srow[i];
    acc += xws[(size_t)r * 64 + lane];
  }
  agg[(size_t)c * 64 + lane] = dinv[c] * acc;
}

// ---------------- gate-preactivation GEMM (bf16 out) --------------------------
__global__ __launch_bounds__(256) void k_gates(
    const float* __restrict__ A, const float* __restrict__ b2,
    const float* __restrict__ WihF, const float* __restrict__ bihF,
    const float* __restrict__ bhhF,
    const float* __restrict__ WihB, const float* __restrict__ bihB,
    const float* __restrict__ bhhB,
    ushort_t* __restrict__ gx) {
  const int dir = blockIdx.x >> 11;
  const int v0 = (blockIdx.x & 2047) * 64;
  const float* Wih = dir ? WihB : WihF;
  const float* bih = dir ? bihB : bihF;
  const float* bhh = dir ? bhhB : bhhF;
  const int t = threadIdx.x;

  float w[64];
#pragma unroll
  for (int k = 0; k < 64; k += 4)
    *reinterpret_cast<float4*>(&w[k]) = *reinterpret_cast<const float4*>(&Wih[t * 64 + k]);
  const float bias = bih[t] + bhh[t];

  __shared__ float xs[64 * 64];
#pragma unroll
  for (int u = 0; u < 16; ++u) {
    int idx = u * 256 + t;
    xs[idx] = fmaxf(A[(size_t)v0 * 64 + idx] + b2[idx & 63], 0.f);
  }
  __syncthreads();

  ushort_t* gp = gx + ((size_t)(dir ? NN_ : 0) + v0) * 256 + t;
  for (int r = 0; r < 64; ++r) {
    const float* xr = &xs[r * 64];
    float a0 = 0.f, a1 = 0.f, a2 = 0.f, a3 = 0.f;
#pragma unroll
    for (int k = 0; k < 64; k += 16) {
      float4 x0 = *reinterpret_cast<const float4*>(&xr[k]);
      float4 x1 = *reinterpret_cast<const float4*>(&xr[k + 4]);
      float4 x2 = *reinterpret_cast<const float4*>(&xr[k + 8]);
      float4 x3 = *reinterpret_cast<const float4*>(&xr[k + 12]);
      a0 = fmaf(x0.x, w[k+0], a0);  a0 = fmaf(x0.y, w[k+1], a0);
      a0 = fmaf(x0.z, w[k+2], a0);  a0 = fmaf(x0.w, w[k+3], a0);
      a1 = fmaf(x1.x, w[k+4], a1);  a1 = fmaf(x1.y, w[k+5], a1);
      a1 = fmaf(x1.z, w[k+6], a1);  a1 = fmaf(x1.w, w[k+7], a1);
      a2 = fmaf(x2.x, w[k+8], a2);  a2 = fmaf(x2.y, w[k+9], a2);
      a2 = fmaf(x2.z, w[k+10], a2); a2 = fmaf(x2.w, w[k+11], a2);
      a3 = fmaf(x3.x, w[k+12], a3); a3 = fmaf(x3.y, w[k+13], a3);
      a3 = fmaf(x3.z, w[k+14], a3); a3 = fmaf(x3.w, w[k+15], a3);
    }
    gp[(size_t)r * 256] = f2bf(bias + (a0 + a1) + (a2 + a3));
  }
}

// ---------------- persistent LSTM: ONE WAVE PER STREAM, no barriers -----------
// 128 blocks x 64 threads. Lane l owns hidden unit l: computes gates
// i/f/g/o for unit l (4 dot-64 against h_{t-1}) + its activation.
// h broadcast via per-wave LDS (in-order DS within a wave => no barrier).
#if __has_builtin(__builtin_amdgcn_fdot2)
#define HAVE_DOT2 1
typedef __fp16 half2v __attribute__((ext_vector_type(2)));   // matches cvt_pkrtz return
#else
#define HAVE_DOT2 0
#endif

__global__ __launch_bounds__(64, 1) void k_lstm3(
    const ushort_t* __restrict__ gx,
    const float* __restrict__ WhhF, const float* __restrict__ WhhB,
    float* __restrict__ y) {
  const int b   = blockIdx.x & 63;
  const int dir = blockIdx.x >> 6;
  const int l   = threadIdx.x;
  const float* Whh = dir ? WhhB : WhhF;

#if HAVE_DOT2
  half2v wp[128];                  // [g4*32 + 2*k4 + {0,1}]
#pragma unroll
  for (int i = 0; i < 64; ++i) {
    const int g4 = i >> 4, k4 = i & 15;
    float4 f4 = *reinterpret_cast<const float4*>(&Whh[(size_t)(g4 * 64 + l) * 64 + 4 * k4]);
    wp[g4 * 32 + 2 * k4]     = __builtin_amdgcn_cvt_pkrtz(f4.x, f4.y);
    wp[g4 * 32 + 2 * k4 + 1] = __builtin_amdgcn_cvt_pkrtz(f4.z, f4.w);
  }
#else
  float wf[256];                   // [g4*64 + k]
#pragma unroll
  for (int i = 0; i < 64; ++i) {
    const int g4 = i >> 4, k4 = i & 15;
    float4 f4 = *reinterpret_cast<const float4*>(&Whh[(size_t)(g4 * 64 + l) * 64 + 4 * k4]);
    wf[g4 * 64 + 4 * k4 + 0] = f4.x;
    wf[g4 * 64 + 4 * k4 + 1] = f4.y;
    wf[g4 * 64 + 4 * k4 + 2] = f4.z;
    wf[g4 * 64 + 4 * k4 + 3] = f4.w;
  }
#endif

  __shared__ __align__(16) float hs[64];
  hs[l] = 0.f;
  float c = 0.f;

  const long stride = dir ? -256 : 256;
  const long ystr   = dir ? -128 : 128;
  const int s0 = dir ? N_ - 1 : 0;
  const ushort_t* p = gx + ((size_t)dir * NN_ + (size_t)b * N_ + s0) * 256 + l;
  float* yp = y + ((size_t)b * N_ + s0) * 128 + (size_t)dir * 64 + l;

  float zc[8][4], zn[8][4];
#pragma unroll
  for (int i = 0; i < 8; ++i)
#pragma unroll
    for (int g4 = 0; g4 < 4; ++g4)
      zc[i][g4] = bf2f(p[i * stride + g4 * 64]);
  p += 8 * stride;

  for (int g = 0; g < N_ / 8; ++g) {
    if (g != N_ / 8 - 1) {
#pragma unroll
      for (int i = 0; i < 8; ++i)
#pragma unroll
        for (int g4 = 0; g4 < 4; ++g4)
          zn[i][g4] = bf2f(p[i * stride + g4 * 64]);
    }
    p += 8 * stride;

    float yv[8];
#pragma unroll
    for (int i = 0; i < 8; ++i) {
      float ai = zc[i][0], af = zc[i][1], ag = zc[i][2], ao = zc[i][3];
#pragma unroll
      for (int k4 = 0; k4 < 16; ++k4) {
        float4 hv = *reinterpret_cast<const float4*>(&hs[4 * k4]);  // broadcast
#if HAVE_DOT2
        half2v hp0 = __builtin_amdgcn_cvt_pkrtz(hv.x, hv.y);
        half2v hp1 = __builtin_amdgcn_cvt_pkrtz(hv.z, hv.w);
        ai = __builtin_amdgcn_fdot2(wp[2*k4],        hp0, ai, false);
        ai = __builtin_amdgcn_fdot2(wp[2*k4+1],      hp1, ai, false);
        af = __builtin_amdgcn_fdot2(wp[32 + 2*k4],   hp0, af, false);
        af = __builtin_amdgcn_fdot2(wp[32 + 2*k4+1], hp1, af, false);
        ag = __builtin_amdgcn_fdot2(wp[64 + 2*k4],   hp0, ag, false);
        ag = __builtin_amdgcn_fdot2(wp[64 + 2*k4+1], hp1, ag, false);
        ao = __builtin_amdgcn_fdot2(wp[96 + 2*k4],   hp0, ao, false);
        ao = __builtin_amdgcn_fdot2(wp[96 + 2*k4+1], hp1, ao, false);
#else
        ai = fmaf(hv.x, wf[4*k4+0], ai); ai = fmaf(hv.y, wf[4*k4+1], ai);
        ai = fmaf(hv.z, wf[4*k4+2], ai); ai = fmaf(hv.w, wf[4*k4+3], ai);
        af = fmaf(hv.x, wf[64+4*k4+0], af); af = fmaf(hv.y, wf[64+4*k4+1], af);
        af = fmaf(hv.z, wf[64+4*k4+2], af); af = fmaf(hv.w, wf[64+4*k4+3], af);
        ag = fmaf(hv.x, wf[128+4*k4+0], ag); ag = fmaf(hv.y, wf[128+4*k4+1], ag);
        ag = fmaf(hv.z, wf[128+4*k4+2], ag); ag = fmaf(hv.w, wf[128+4*k4+3], ag);
        ao = fmaf(hv.x, wf[192+4*k4+0], ao); ao = fmaf(hv.y, wf[192+4*k4+1], ao);
        ao = fmaf(hv.z, wf[192+4*k4+2], ao); ao = fmaf(hv.w, wf[192+4*k4+3], ao);
#endif
      }
      float si_ = __fdividef(1.f, 1.f + __expf(-ai));
      float sf  = __fdividef(1.f, 1.f + __expf(-af));
      float so  = __fdividef(1.f, 1.f + __expf(-ao));
      float tg  = 1.f - __fdividef(2.f, __expf(2.f * ag) + 1.f);
      c = sf * c + si_ * tg;
      float tc = 1.f - __fdividef(2.f, __expf(2.f * c) + 1.f);
      float hh = so * tc;
      hs[l] = hh;            // in-order DS within the wave: next step's reads see it
      yv[i] = hh;
    }
#pragma unroll
    for (int i = 0; i < 8; ++i) yp[(long)i * ystr] = yv[i];
    yp += 8 * ystr;
#pragma unroll
    for (int i = 0; i < 8; ++i)
#pragma unroll
      for (int g4 = 0; g4 < 4; ++g4) zc[i][g4] = zn[i][g4];
  }
}

// ---------------- fallback persistent LSTM (round-3 version, safe path) -------
__global__ __launch_bounds__(256) void k_lstm(
    const float* __restrict__ h2raw, const float* __restrict__ b2,
    const float* __restrict__ WihF, const float* __restrict__ WhhF,
    const float* __restrict__ bihF, const float* __restrict__ bhhF,
    const float* __restrict__ WihB, const float* __restrict__ WhhB,
    const float* __restrict__ bihB, const float* __restrict__ bhhB,
    float* __restrict__ y) {
  const int b   = blockIdx.x & 63;
  const int dir = blockIdx.x >> 6;
  const float* Wih = dir ? WihB : WihF;
  const float* Whh = dir ? WhhB : WhhF;
  const float* bih = dir ? bihB : bihF;
  const float* bhh = dir ? bhhB : bhhF;
  const int j = threadIdx.x;

  float wih[64], whh[64];
#pragma unroll
  for (int k = 0; k < 64; k += 4) {
    *reinterpret_cast<float4*>(&wih[k]) = *reinterpret_cast<const float4*>(&Wih[j * 64 + k]);
    *reinterpret_cast<float4*>(&whh[k]) = *reinterpret_cast<const float4*>(&Whh[j * 64 + k]);
  }
  const float bias = bih[j] + bhh[j];
  const float b2j = (j < 64) ? b2[j] : 0.f;

  __shared__ __align__(16) float xbuf[64];
  __shared__ __align__(16) float hbuf[64];
  __shared__ float gbuf[256];
  float c = 0.f;
  if (j < 64) hbuf[j] = 0.f;

  float xc = 0.f, xn = 0.f;
  if (j < 64) {
    const int s0 = dir ? N_ - 1 : 0;
    const int s1 = dir ? N_ - 2 : 1;
    xc = h2raw[((size_t)b * N_ + s0) * 64 + j];
    xn = h2raw[((size_t)b * N_ + s1) * 64 + j];
  }

  for (int si = 0; si < N_; ++si) {
    const int s = dir ? (N_ - 1 - si) : si;
    const size_t vrow = (size_t)b * N_ + s;
    if (j < 64) xbuf[j] = fmaxf(xc + b2j, 0.f);
    LBAR();

    float xp = 0.f;
    {
      int si2 = si + 2; if (si2 >= N_) si2 = N_ - 1;
      const int s2 = dir ? (N_ - 1 - si2) : si2;
      if (j < 64) xp = h2raw[((size_t)b * N_ + s2) * 64 + j];
    }

    float a0 = 0.f, a1 = 0.f, a2 = 0.f, a3 = 0.f;
#pragma unroll
    for (int k = 0; k < 64; k += 16) {
      float4 xv0 = *reinterpret_cast<const float4*>(&xbuf[k]);
      float4 hv0 = *reinterpret_cast<const float4*>(&hbuf[k]);
      a0 = fmaf(xv0.x, wih[k+0], a0); a0 = fmaf(hv0.x, whh[k+0], a0);
      a0 = fmaf(xv0.y, wih[k+1], a0); a0 = fmaf(hv0.y, whh[k+1], a0);
      a0 = fmaf(xv0.z, wih[k+2], a0); a0 = fmaf(hv0.z, whh[k+2], a0);
      a0 = fmaf(xv0.w, wih[k+3], a0); a0 = fmaf(hv0.w, whh[k+3], a0);
      float4 xv1 = *reinterpret_cast<const float4*>(&xbuf[k+4]);
      float4 hv1 = *reinterpret_cast<const float4*>(&hbuf[k+4]);
      a1 = fmaf(xv1.x, wih[k+4], a1); a1 = fmaf(hv1.x, whh[k+4], a1);
      a1 = fmaf(xv1.y, wih[k+5], a1); a1 = fmaf(hv1.y, whh[k+5], a1);
      a1 = fmaf(xv1.z, wih[k+6], a1); a1 = fmaf(hv1.z, whh[k+6], a1);
      a1 = fmaf(xv1.w, wih[k+7], a1); a1 = fmaf(hv1.w, whh[k+7], a1);
      float4 xv2 = *reinterpret_cast<const float4*>(&xbuf[k+8]);
      float4 hv2 = *reinterpret_cast<const float4*>(&hbuf[k+8]);
      a2 = fmaf(xv2.x, wih[k+8], a2); a2 = fmaf(hv2.x, whh[k+8], a2);
      a2 = fmaf(xv2.y, wih[k+9], a2); a2 = fmaf(hv2.y, whh[k+9], a2);
      a2 = fmaf(xv2.z, wih[k+10], a2); a2 = fmaf(hv2.z, whh[k+10], a2);
      a2 = fmaf(xv2.w, wih[k+11], a2); a2 = fmaf(hv2.w, whh[k+11], a2);
      float4 xv3 = *reinterpret_cast<const float4*>(&xbuf[k+12]);
      float4 hv3 = *reinterpret_cast<const float4*>(&hbuf[k+12]);
      a3 = fmaf(xv3.x, wih[k+12], a3); a3 = fmaf(hv3.x, whh[k+12], a3);
      a3 = fmaf(xv3.y, wih[k+13], a3); a3 = fmaf(hv3.y, whh[k+13], a3);
      a3 = fmaf(xv3.z, wih[k+14], a3); a3 = fmaf(hv3.z, whh[k+14], a3);
      a3 = fmaf(xv3.w, wih[k+15], a3); a3 = fmaf(hv3.w, whh[k+15], a3);
    }
    gbuf[j] = bias + (a0 + a1) + (a2 + a3);
    LBAR();

    if (j < 64) {
      float gi = gbuf[j], gf = gbuf[64 + j], gg = gbuf[128 + j], go = gbuf[192 + j];
      float si_ = __fdividef(1.f, 1.f + __expf(-gi));
      float sf  = __fdividef(1.f, 1.f + __expf(-gf));
      float so  = __fdividef(1.f, 1.f + __expf(-go));
      float tg  = 1.f - __fdividef(2.f, __expf(2.f * gg) + 1.f);
      c = sf * c + si_ * tg;
      float tc = 1.f - __fdividef(2.f, __expf(2.f * c) + 1.f);
      float hh = so * tc;
      hbuf[j] = hh;
      y[vrow * 128 + (size_t)dir * 64 + j] = hh;
    }
    xc = xn; xn = xp;
  }
}

// ---------------- decoder + masked MSE (LDS-staged y rows) ----------------
__global__ __launch_bounds__(256) void k_decoder(
    const float* __restrict__ y, const float* __restrict__ x,
    const float* __restrict__ mask, const float* __restrict__ Wd,
    const float* __restrict__ bd, float* __restrict__ out,
    float* __restrict__ accum) {
  __shared__ float ys[16 * 132];           // 16 rows, padded to 132 floats
  const int tid = threadIdx.x;
  const size_t base = (size_t)blockIdx.x * 2048;
#pragma unroll
  for (int u = 0; u < 2; ++u) {
    int idx = u * 1024 + tid * 4;
    *reinterpret_cast<float4*>(&ys[(idx >> 7) * 132 + (idx & 127)]) =
        *reinterpret_cast<const float4*>(&y[base + idx]);
  }
  __syncthreads();
  size_t v = (size_t)blockIdx.x * 16 + (tid >> 4);
  int f = tid & 15;
  const float* yr = &ys[(tid >> 4) * 132];
  float acc = bd[f];
#pragma unroll
  for (int jj = 0; jj < 128; jj += 4) {
    float4 yv = *reinterpret_cast<const float4*>(&yr[jj]);
    float4 wv = *reinterpret_cast<const float4*>(&Wd[f * 128 + jj]);
    acc = fmaf(yv.x, wv.x, acc); acc = fmaf(yv.y, wv.y, acc);
    acc = fmaf(yv.z, wv.z, acc); acc = fmaf(yv.w, wv.w, acc);
  }
  size_t o = v * 16 + f;
  float xv = x[o], m = mask[o];
  float d = acc - xv;
  out[o] = (m != 0.f) ? xv : acc;
  float num = m * d * d;
  float den = m;
#pragma unroll
  for (int off = 32; off > 0; off >>= 1) {
    num += __shfl_down(num, off);
    den += __shfl_down(den, off);
  }
  if ((tid & 63) == 0) {
    unsafeAtomicAdd(&accum[0], num);
    unsafeAtomicAdd(&accum[1], den);
  }
}

__global__ void k_loss(const float* __restrict__ accum, float* __restrict__ out_loss) {
  if (threadIdx.x == 0) out_loss[0] = accum[0] / (accum[1] + 1e-8f);
}

// ---------------- launch ----------------
extern "C" void kernel_launch(void* const* d_in, const int* in_sizes, int n_in,
                              void* d_out, int out_size, void* d_ws, size_t ws_size,
                              hipStream_t stream) {
  const float* x    = (const float*)d_in[0];
  const int*   ei   = (const int*)d_in[1];   // row = ei, col = ei + E_
  const float* mask = (const float*)d_in[2];
  const float* W1 = (const float*)d_in[3];
  const float* b1 = (const float*)d_in[4];
  const float* W2 = (const float*)d_in[5];
  const float* b2 = (const float*)d_in[6];
  const float* WihF = (const float*)d_in[7];
  const float* WhhF = (const float*)d_in[8];
  const float* bihF = (const float*)d_in[9];
  const float* bhhF = (const float*)d_in[10];
  const float* WihB = (const float*)d_in[11];
  const float* WhhB = (const float*)d_in[12];
  const float* bihB = (const float*)d_in[13];
  const float* bhhB = (const float*)d_in[14];
  const float* Wd = (const float*)d_in[15];
  const float* bd = (const float*)d_in[16];
  float* out = (float*)d_out;

  // layout: dinv | accum | Y(67M) | C(33.5M) | A(33.5M, gx overlays A +134M)
  float* dinv  = (float*)d_ws;
  float* accum = dinv + NN_;
  float* Y     = accum + 64;
  float* C     = Y + (size_t)NN_ * 128;
  float* A     = C + (size_t)NN_ * 64;
  ushort_t* gx = (ushort_t*)A;
  // sort scratch overlays Y (dead until LSTM writes it)
  int*    srow   = (int*)Y;
  uint_t* cnt    = (uint_t*)(srow + E_);
  uint_t* start  = cnt + NN_;
  uint_t* cursor = start + NN_ + 1;
  uint_t* bsum   = cursor + NN_;

  size_t need = ((char*)A - (char*)d_ws) + 2ull * NN_ * 256 * sizeof(ushort_t);
  bool use_gx = ws_size >= need;

  // ---- degree + col-sort ----
  k_zero<<<NN_ / 256, 256, 0, stream>>>(cnt, accum);
  k_hist<<<E_ / 256, 256, 0, stream>>>(ei + E_, cnt);
  k_dinvc<<<NN_ / 256, 256, 0, stream>>>(cnt, dinv);
  k_bsum<<<512, 256, 0, stream>>>(cnt, bsum);
  k_scan512<<<1, 512, 0, stream>>>(bsum);
  k_scanadd<<<512, 256, 0, stream>>>(cnt, bsum, start, cursor);
  k_place<<<E_ / 256, 256, 0, stream>>>(ei, ei + E_, cursor, srow);

  // ---- GCN layer 1 ----
  k_gemm<FIN_, false><<<NN_ / 4, 256, 0, stream>>>(x, W1, nullptr, dinv, A);
  k_colagg<<<NN_ / 4, 256, 0, stream>>>(srow, start, dinv, A, C);

  // ---- GCN layer 2 ----
  k_gemm<64, true><<<NN_ / 4, 256, 0, stream>>>(C, W2, b1, dinv, A);
  k_colagg<<<NN_ / 4, 256, 0, stream>>>(srow, start, dinv, A, C);

  if (use_gx) {
    k_gates<<<2 * (NN_ / 64), 256, 0, stream>>>(C, b2, WihF, bihF, bhhF,
                                                WihB, bihB, bhhB, gx);
    k_lstm3<<<128, 64, 0, stream>>>(gx, WhhF, WhhB, Y);
  } else {
    k_lstm<<<128, 256, 0, stream>>>(C, b2, WihF, WhhF, bihF, bhhF,
                                    WihB, WhhB, bihB, bhhB, Y);
  }

  k_decoder<<<NN_ / 16, 256, 0, stream>>>(Y, x, mask, Wd, bd, out, accum);
  k_loss<<<1, 64, 0, stream>>>(accum, out + (size_t)NN_ * FIN_);
}